// Round 6
// baseline (559.328 us; speedup 1.0000x reference)
//
#include <hip/hip_runtime.h>
#include <math.h>

#define N_NODES 50000
#define N_EDGES 800000
#define N_GRAPHS 64
#define F_INN 128
#define F_HID 192
#define F_OUTT 128
#define N_CLS 10
#define POOL_CHUNK 128

typedef short short8 __attribute__((ext_vector_type(8)));
typedef float f32x4 __attribute__((ext_vector_type(4)));

static __device__ inline unsigned short f2bf(float f) {
    unsigned int u = __float_as_uint(f);
    unsigned int r = (u + 0x7FFFu + ((u >> 16) & 1u)) >> 16;  // RNE
    return (unsigned short)r;
}
static __device__ inline float bf2f(unsigned short h) {
    return __uint_as_float(((unsigned int)h) << 16);
}

// ---------------- CSR build ----------------
// 4 edges/thread: int4 coalesced row load, 4 independent atomic chains.
__global__ void k_deg(const int* __restrict__ row, int* __restrict__ cnt) {
    int e0 = (blockIdx.x * 256 + threadIdx.x) * 4;
    if (e0 + 4 <= N_EDGES) {
        int4 r4 = *(const int4*)(row + e0);
        atomicAdd(&cnt[r4.x], 1);
        atomicAdd(&cnt[r4.y], 1);
        atomicAdd(&cnt[r4.z], 1);
        atomicAdd(&cnt[r4.w], 1);
    } else {
        for (int e = e0; e < N_EDGES; e++) atomicAdd(&cnt[row[e]], 1);
    }
}

// scan phase 1 + fused dis = rsqrt(deg)
__global__ void k_scan1(const int* __restrict__ cnt, int* __restrict__ rp,
                        int* __restrict__ part, float* __restrict__ dis) {
    __shared__ int s[256];
    int base = blockIdx.x * 512;
    int i0 = base + 2 * threadIdx.x;
    int v0 = (i0 < N_NODES) ? cnt[i0] : 0;
    int v1 = (i0 + 1 < N_NODES) ? cnt[i0 + 1] : 0;
    if (i0 < N_NODES) dis[i0] = v0 > 0 ? rsqrtf((float)v0) : 0.f;
    if (i0 + 1 < N_NODES) dis[i0 + 1] = v1 > 0 ? rsqrtf((float)v1) : 0.f;
    int tsum = v0 + v1;
    s[threadIdx.x] = tsum;
    __syncthreads();
    for (int off = 1; off < 256; off <<= 1) {
        int val = (threadIdx.x >= off) ? s[threadIdx.x - off] : 0;
        __syncthreads();
        s[threadIdx.x] += val;
        __syncthreads();
    }
    int excl = s[threadIdx.x] - tsum;
    if (i0 < N_NODES) rp[i0] = excl;
    if (i0 + 1 < N_NODES) rp[i0 + 1] = excl + v0;
    if (threadIdx.x == 255) part[blockIdx.x] = s[255];
}

__global__ void k_scan2(int* __restrict__ part, int nb) {
    __shared__ int s[128];
    int t = threadIdx.x;
    int v = (t < nb) ? part[t] : 0;
    s[t] = v;
    __syncthreads();
    for (int off = 1; off < 128; off <<= 1) {
        int val = (t >= off) ? s[t - off] : 0;
        __syncthreads();
        s[t] += val;
        __syncthreads();
    }
    if (t < nb) part[t] = s[t] - v;  // exclusive
}

// scan phase 3; also seeds fill[i] = final rp[i] so scatter needs no rp load
__global__ void k_scan3(int* __restrict__ rp, const int* __restrict__ part,
                        int* __restrict__ fill) {
    int add = part[blockIdx.x];
    int i0 = blockIdx.x * 512 + 2 * threadIdx.x;
    if (i0 < N_NODES) {
        int v = rp[i0] + add;
        rp[i0] = v;
        fill[i0] = v;
    }
    if (i0 + 1 < N_NODES) {
        int v = rp[i0 + 1] + add;
        rp[i0 + 1] = v;
        fill[i0 + 1] = v;
    }
    if (blockIdx.x == 0 && threadIdx.x == 0) rp[N_NODES] = N_EDGES;
}

// packed CSR payload: (col, weight-bits). 4 edges/thread, independent chains;
// position comes straight from atomicAdd on pre-seeded fill.
__global__ void k_scatter(const int* __restrict__ row, const int* __restrict__ col,
                          const float* __restrict__ dis, int* __restrict__ fill,
                          int2* __restrict__ cw) {
    int e0 = (blockIdx.x * 256 + threadIdx.x) * 4;
    if (e0 + 4 <= N_EDGES) {
        int4 r4 = *(const int4*)(row + e0);
        int4 c4 = *(const int4*)(col + e0);
        int r[4] = {r4.x, r4.y, r4.z, r4.w};
        int c[4] = {c4.x, c4.y, c4.z, c4.w};
        float dr[4], dc[4];
#pragma unroll
        for (int u = 0; u < 4; u++) {
            dr[u] = dis[r[u]];
            dc[u] = dis[c[u]];
        }
        int pos[4];
#pragma unroll
        for (int u = 0; u < 4; u++) pos[u] = atomicAdd(&fill[r[u]], 1);
#pragma unroll
        for (int u = 0; u < 4; u++) {
            int2 v;
            v.x = c[u];
            v.y = __float_as_int(-dr[u] * dc[u]);
            cw[pos[u]] = v;
        }
    } else {
        for (int e = e0; e < N_EDGES; e++) {
            int r = row[e], c = col[e];
            int pos = atomicAdd(&fill[r], 1);
            int2 v;
            v.x = c;
            v.y = __float_as_int(-dis[r] * dis[c]);
            cw[pos] = v;
        }
    }
}

// ---------------- fused fp32->bf16 conversions (x + 3 transposed W) --------
#define NX (N_NODES * F_INN)
#define NW1 (3 * 128 * 192)
#define NW2 (3 * 192 * 192)
#define NW3 (3 * 192 * 128)
__global__ void k_convAll(const float* __restrict__ x, const float* __restrict__ W1,
                          const float* __restrict__ W2, const float* __restrict__ W3,
                          unsigned short* __restrict__ xb,
                          unsigned short* __restrict__ Wt1,
                          unsigned short* __restrict__ Wt2,
                          unsigned short* __restrict__ Wt3) {
    int idx = blockIdx.x * 256 + threadIdx.x;
    if (idx < NX) {
        xb[idx] = f2bf(x[idx]);
        return;
    }
    idx -= NX;
    if (idx < NW1) {  // W1[j][k][n] -> Wt1[j][n][k], Fin=128, Fout=192
        int per = 128 * 192;
        int j = idx / per, r = idx - j * per;
        int k = r / 192, n = r - k * 192;
        Wt1[j * per + n * 128 + k] = f2bf(W1[idx]);
        return;
    }
    idx -= NW1;
    if (idx < NW2) {  // Fin=192, Fout=192
        int per = 192 * 192;
        int j = idx / per, r = idx - j * per;
        int k = r / 192, n = r - k * 192;
        Wt2[j * per + n * 192 + k] = f2bf(W2[idx]);
        return;
    }
    idx -= NW2;
    if (idx < NW3) {  // Fin=192, Fout=128
        int per = 192 * 128;
        int j = idx / per, r = idx - j * per;
        int k = r / 128, n = r - k * 128;
        Wt3[j * per + n * 192 + k] = f2bf(W3[idx]);
    }
}

// ---------------- SpMV (bf16 in/out, fp32 accum) ----------------
// y = alpha*(L_hat@h) + beta*z. One wave per row. Lane l owns feats
// {2l, 2l+1} (packed uint gather) + feat 128+l (ushort) for F=192.
// Edge metadata (rp bounds, col, w) is wave-uniform -> readfirstlane
// scalarizes address math + weight operand; edge loop unrolled x8 so
// 8 (16 for F=192) gather latency chains overlap.
template <int F>
__global__ void k_spmv(const int* __restrict__ rp, const int2* __restrict__ cw,
                       const unsigned short* __restrict__ h,
                       const unsigned short* __restrict__ z, float alpha, float beta,
                       unsigned short* __restrict__ y) {
    constexpr bool EX = (F > 128);
    constexpr int FU = F / 2;  // uints per row
    int wave = threadIdx.x >> 6;
    int lane = threadIdx.x & 63;
    int r = blockIdx.x * 4 + wave;
    if (r >= N_NODES) return;
    int e0 = __builtin_amdgcn_readfirstlane(rp[r]);
    int e1 = __builtin_amdgcn_readfirstlane(rp[r + 1]);
    const unsigned int* hu = (const unsigned int*)h;
    float a0 = 0.f, a1 = 0.f, a2 = 0.f;
    int e = e0;
    for (; e + 8 <= e1; e += 8) {
        int colv[8];
        float wv[8];
#pragma unroll
        for (int u = 0; u < 8; u++) {
            int2 p = cw[e + u];
            colv[u] = __builtin_amdgcn_readfirstlane(p.x);
            wv[u] = __uint_as_float(__builtin_amdgcn_readfirstlane(p.y));
        }
        unsigned int g[8];
        unsigned short s[8];
#pragma unroll
        for (int u = 0; u < 8; u++) {
            g[u] = hu[colv[u] * FU + lane];
            if constexpr (EX) s[u] = h[colv[u] * F + 128 + lane];
        }
#pragma unroll
        for (int u = 0; u < 8; u++) {
            a0 += wv[u] * bf2f((unsigned short)g[u]);
            a1 += wv[u] * bf2f((unsigned short)(g[u] >> 16));
            if constexpr (EX) a2 += wv[u] * bf2f(s[u]);
        }
    }
    for (; e + 4 <= e1; e += 4) {
        int colv[4];
        float wv[4];
#pragma unroll
        for (int u = 0; u < 4; u++) {
            int2 p = cw[e + u];
            colv[u] = __builtin_amdgcn_readfirstlane(p.x);
            wv[u] = __uint_as_float(__builtin_amdgcn_readfirstlane(p.y));
        }
        unsigned int g[4];
        unsigned short s[4];
#pragma unroll
        for (int u = 0; u < 4; u++) {
            g[u] = hu[colv[u] * FU + lane];
            if constexpr (EX) s[u] = h[colv[u] * F + 128 + lane];
        }
#pragma unroll
        for (int u = 0; u < 4; u++) {
            a0 += wv[u] * bf2f((unsigned short)g[u]);
            a1 += wv[u] * bf2f((unsigned short)(g[u] >> 16));
            if constexpr (EX) a2 += wv[u] * bf2f(s[u]);
        }
    }
    for (; e < e1; e++) {
        int2 p = cw[e];
        int c = __builtin_amdgcn_readfirstlane(p.x);
        float w = __uint_as_float(__builtin_amdgcn_readfirstlane(p.y));
        unsigned int g = hu[c * FU + lane];
        a0 += w * bf2f((unsigned short)g);
        a1 += w * bf2f((unsigned short)(g >> 16));
        if constexpr (EX) a2 += w * bf2f(h[c * F + 128 + lane]);
    }
    float v0 = alpha * a0, v1 = alpha * a1, v2 = alpha * a2;
    if (beta != 0.f) {
        unsigned int zg = ((const unsigned int*)z)[r * FU + lane];
        v0 += beta * bf2f((unsigned short)zg);
        v1 += beta * bf2f((unsigned short)(zg >> 16));
        if constexpr (EX) v2 += beta * bf2f(z[r * F + 128 + lane]);
    }
    ((unsigned int*)y)[r * FU + lane] =
        (unsigned int)f2bf(v0) | ((unsigned int)f2bf(v1) << 16);
    if constexpr (EX) y[r * F + 128 + lane] = f2bf(v2);
}

// ---------------- fused 3-matrix bf16 MFMA GEMM ----------------
// C = A0@W[0]+A1@W[1]+A2@W[2]+bias, A row-major [M][Fin] bf16,
// Wt pre-transposed [3][Fout][Fin] bf16, C bf16 [M][Fout].
// Block: 256 thr = 4 waves; tile M=128 x N=64; wave = 32 rows x 64 cols
// = 2x4 grid of 16x16x32 MFMAs. LDS stride 40 shorts breaks pow-2 conflicts.
__global__ __launch_bounds__(256) void k_gemm3(
    const unsigned short* __restrict__ A0, const unsigned short* __restrict__ A1,
    const unsigned short* __restrict__ A2, const unsigned short* __restrict__ Wt,
    const float* __restrict__ bias, unsigned short* __restrict__ C, int Fin,
    int Fout) {
    __shared__ unsigned short As[128 * 40];
    __shared__ unsigned short Bs[64 * 40];
    int t = threadIdx.x;
    int w = t >> 6;
    int lane = t & 63;
    int ml = lane & 15;
    int quad = lane >> 4;
    int mBase = blockIdx.x * 128;
    int nBase = blockIdx.y * 64;
    int per = Fin * Fout;

    f32x4 acc[2][4];
#pragma unroll
    for (int i = 0; i < 2; i++)
#pragma unroll
        for (int jn = 0; jn < 4; jn++) acc[i][jn] = (f32x4){0.f, 0.f, 0.f, 0.f};

    int srow = t >> 2;   // 0..63
    int schunk = t & 3;  // 16B chunk within 32-k slab
    int nChunks = (3 * Fin) >> 5;

    for (int ch = 0; ch < nChunks; ch++) {
        int kg = ch << 5;
        int j = kg / Fin;
        int kk = kg - j * Fin;
        const unsigned short* Aj = (j == 0) ? A0 : (j == 1) ? A1 : A2;
        if (ch > 0) __syncthreads();
#pragma unroll
        for (int pass = 0; pass < 2; pass++) {
            int row = srow + pass * 64;
            int gm = mBase + row;
            uint4 v = {0u, 0u, 0u, 0u};
            if (gm < N_NODES)
                v = *(const uint4*)(Aj + (size_t)gm * Fin + kk + schunk * 8);
            *(uint4*)&As[row * 40 + schunk * 8] = v;
        }
        {
            const unsigned short* src =
                Wt + (size_t)j * per + (size_t)(nBase + srow) * Fin + kk + schunk * 8;
            *(uint4*)&Bs[srow * 40 + schunk * 8] = *(const uint4*)src;
        }
        __syncthreads();

        short8 afr[2], bfr[4];
#pragma unroll
        for (int i = 0; i < 2; i++)
            afr[i] = *(const short8*)&As[(w * 32 + i * 16 + ml) * 40 + quad * 8];
#pragma unroll
        for (int jn = 0; jn < 4; jn++)
            bfr[jn] = *(const short8*)&Bs[(jn * 16 + ml) * 40 + quad * 8];
#pragma unroll
        for (int i = 0; i < 2; i++)
#pragma unroll
            for (int jn = 0; jn < 4; jn++)
                acc[i][jn] = __builtin_amdgcn_mfma_f32_16x16x32_bf16(
                    afr[i], bfr[jn], acc[i][jn], 0, 0, 0);
    }

    float biasv[4];
#pragma unroll
    for (int jn = 0; jn < 4; jn++) biasv[jn] = bias[nBase + jn * 16 + ml];

#pragma unroll
    for (int i = 0; i < 2; i++) {
#pragma unroll
        for (int r = 0; r < 4; r++) {
            int m = mBase + w * 32 + i * 16 + quad * 4 + r;
            if (m < N_NODES) {
                unsigned short* cp = C + (size_t)m * Fout + nBase + ml;
#pragma unroll
                for (int jn = 0; jn < 4; jn++)
                    cp[jn * 16] = f2bf(acc[i][jn][r] + biasv[jn]);
            }
        }
    }
}

// ---------------- pooling: chunked partial sums + atomics ----------------
__global__ void k_pool_partial(const unsigned short* __restrict__ h,
                               const int* __restrict__ batch,
                               float* __restrict__ psum, int* __restrict__ pcnt) {
    int f = threadIdx.x;  // 128
    int n0 = blockIdx.x * POOL_CHUNK;
    int n1 = n0 + POOL_CHUNK;
    if (n1 > N_NODES) n1 = N_NODES;
    if (n0 >= N_NODES) return;
    int curg = batch[n0];
    float acc = 0.f;
    int run = 0;
    for (int n = n0; n < n1; n++) {
        int g = batch[n];
        if (g != curg) {
            atomicAdd(&psum[curg * F_OUTT + f], acc);
            if (f == 0) atomicAdd(&pcnt[curg], run);
            acc = 0.f;
            run = 0;
            curg = g;
        }
        acc += bf2f(h[(size_t)n * F_OUTT + f]);
        run++;
    }
    atomicAdd(&psum[curg * F_OUTT + f], acc);
    if (f == 0) atomicAdd(&pcnt[curg], run);
}

__global__ void k_head(const float* __restrict__ psum, const int* __restrict__ pcnt,
                       const float* __restrict__ fcw, const float* __restrict__ fcb,
                       float* __restrict__ out) {
    int g = blockIdx.x;
    int c = threadIdx.x;  // 64 threads, lanes >= N_CLS idle
    __shared__ float sl[N_CLS];
    float inv = 1.f / fmaxf((float)pcnt[g], 1.f);
    float l = 0.f;
    if (c < N_CLS) {
        l = fcb[c];
        for (int k = 0; k < F_OUTT; k++)
            l += psum[g * F_OUTT + k] * inv * fcw[k * N_CLS + c];
        sl[c] = l;
    }
    __syncthreads();
    if (c < N_CLS) {
        float m = -1e30f;
        for (int i = 0; i < N_CLS; i++) m = fmaxf(m, sl[i]);
        float s = 0.f;
        for (int i = 0; i < N_CLS; i++) s += expf(sl[i] - m);
        out[g * N_CLS + c] = l - m - logf(s);
    }
}

extern "C" void kernel_launch(void* const* d_in, const int* in_sizes, int n_in,
                              void* d_out, int out_size, void* d_ws, size_t ws_size,
                              hipStream_t stream) {
    const float* x = (const float*)d_in[0];
    const int* ei = (const int*)d_in[1];
    const int* batch = (const int*)d_in[2];
    const float* W1 = (const float*)d_in[3];
    const float* b1 = (const float*)d_in[4];
    const float* W2 = (const float*)d_in[5];
    const float* b2 = (const float*)d_in[6];
    const float* W3 = (const float*)d_in[7];
    const float* b3 = (const float*)d_in[8];
    const float* fcw = (const float*)d_in[9];
    const float* fcb = (const float*)d_in[10];
    float* out = (float*)d_out;
    const int* row = ei;
    const int* col = ei + N_EDGES;

    char* p = (char*)d_ws;
    auto carve = [&](size_t bytes) {
        char* q = p;
        p += (bytes + 255) & ~(size_t)255;
        return q;
    };
    int* cnt = (int*)carve(N_NODES * 4);
    int* fill = (int*)carve(N_NODES * 4);
    float* dis = (float*)carve(N_NODES * 4);
    int* rp = (int*)carve((N_NODES + 1) * 4);
    int* part = (int*)carve(128 * 4);
    int2* cw = (int2*)carve((size_t)N_EDGES * 8);
    unsigned short* xb = (unsigned short*)carve((size_t)N_NODES * F_INN * 2);
    size_t hbytes = (size_t)N_NODES * 192 * 2;
    unsigned short* bufA = (unsigned short*)carve(hbytes);
    unsigned short* bufB = (unsigned short*)carve(hbytes);
    unsigned short* bufC = (unsigned short*)carve(hbytes);
    unsigned short* bufD = (unsigned short*)carve(hbytes);
    unsigned short* Wt1 = (unsigned short*)carve(NW1 * 2);
    unsigned short* Wt2 = (unsigned short*)carve(NW2 * 2);
    unsigned short* Wt3 = (unsigned short*)carve(NW3 * 2);
    float* psum = (float*)carve(N_GRAPHS * F_OUTT * 4);
    int* pcnt = (int*)carve(N_GRAPHS * 4);

    hipMemsetAsync(cnt, 0, N_NODES * 4, stream);
    hipMemsetAsync(psum, 0, N_GRAPHS * F_OUTT * 4, stream);
    hipMemsetAsync(pcnt, 0, N_GRAPHS * 4, stream);

    k_deg<<<(N_EDGES / 4 + 255) / 256, 256, 0, stream>>>(row, cnt);
    int nb = (N_NODES + 511) / 512;  // 98
    k_scan1<<<nb, 256, 0, stream>>>(cnt, rp, part, dis);
    k_scan2<<<1, 128, 0, stream>>>(part, nb);
    k_scan3<<<nb, 256, 0, stream>>>(rp, part, fill);
    k_scatter<<<(N_EDGES / 4 + 255) / 256, 256, 0, stream>>>(row, col, dis, fill, cw);

    {
        int tot = NX + NW1 + NW2 + NW3;
        k_convAll<<<(tot + 255) / 256, 256, 0, stream>>>(x, W1, W2, W3, xb, Wt1, Wt2,
                                                         Wt3);
    }

    const int spmvGrid = (N_NODES + 3) / 4;

    // Layer 1: in=xb (128) -> out=bufA (192)
    k_spmv<128><<<spmvGrid, 256, 0, stream>>>(rp, cw, xb, xb, 1.f, 0.f, bufB);
    k_spmv<128><<<spmvGrid, 256, 0, stream>>>(rp, cw, bufB, xb, 2.f, -1.f, bufC);
    {
        dim3 g((N_NODES + 127) / 128, 192 / 64);
        k_gemm3<<<g, 256, 0, stream>>>(xb, bufB, bufC, Wt1, b1, bufA, 128, 192);
    }
    // Layer 2: in=bufA (192) -> out=bufD (192)
    k_spmv<192><<<spmvGrid, 256, 0, stream>>>(rp, cw, bufA, bufA, 1.f, 0.f, bufB);
    k_spmv<192><<<spmvGrid, 256, 0, stream>>>(rp, cw, bufB, bufA, 2.f, -1.f, bufC);
    {
        dim3 g((N_NODES + 127) / 128, 192 / 64);
        k_gemm3<<<g, 256, 0, stream>>>(bufA, bufB, bufC, Wt2, b2, bufD, 192, 192);
    }
    // Layer 3: in=bufD (192) -> out=bufA (128)
    k_spmv<192><<<spmvGrid, 256, 0, stream>>>(rp, cw, bufD, bufD, 1.f, 0.f, bufB);
    k_spmv<192><<<spmvGrid, 256, 0, stream>>>(rp, cw, bufB, bufD, 2.f, -1.f, bufC);
    {
        dim3 g((N_NODES + 127) / 128, 128 / 64);
        k_gemm3<<<g, 256, 0, stream>>>(bufD, bufB, bufC, Wt3, b3, bufA, 192, 128);
    }

    k_pool_partial<<<(N_NODES + POOL_CHUNK - 1) / POOL_CHUNK, F_OUTT, 0, stream>>>(
        bufA, batch, psum, pcnt);
    k_head<<<N_GRAPHS, 64, 0, stream>>>(psum, pcnt, fcw, fcb, out);
}

// Round 7
// 538.356 us; speedup vs baseline: 1.0390x; 1.0390x over previous
//
#include <hip/hip_runtime.h>
#include <math.h>

#define N_NODES 50000
#define N_EDGES 800000
#define N_GRAPHS 64
#define F_INN 128
#define F_HID 192
#define F_OUTT 128
#define N_CLS 10
#define POOL_CHUNK 128

typedef short short8 __attribute__((ext_vector_type(8)));
typedef float f32x4 __attribute__((ext_vector_type(4)));

static __device__ inline unsigned short f2bf(float f) {
    unsigned int u = __float_as_uint(f);
    unsigned int r = (u + 0x7FFFu + ((u >> 16) & 1u)) >> 16;  // RNE
    return (unsigned short)r;
}
static __device__ inline float bf2f(unsigned short h) {
    return __uint_as_float(((unsigned int)h) << 16);
}

// ---------------- CSR build ----------------
// 1 edge/thread: random-atomic work is TLP-limited, not ILP-limited
// (round-6 4-edge/thread variant dropped occupancy 49%->20% and regressed).
__global__ void k_deg(const int* __restrict__ row, int* __restrict__ cnt) {
    int e = blockIdx.x * 256 + threadIdx.x;
    if (e < N_EDGES) atomicAdd(&cnt[row[e]], 1);
}

// scan phase 1 + fused dis = rsqrt(deg)
__global__ void k_scan1(const int* __restrict__ cnt, int* __restrict__ rp,
                        int* __restrict__ part, float* __restrict__ dis) {
    __shared__ int s[256];
    int base = blockIdx.x * 512;
    int i0 = base + 2 * threadIdx.x;
    int v0 = (i0 < N_NODES) ? cnt[i0] : 0;
    int v1 = (i0 + 1 < N_NODES) ? cnt[i0 + 1] : 0;
    if (i0 < N_NODES) dis[i0] = v0 > 0 ? rsqrtf((float)v0) : 0.f;
    if (i0 + 1 < N_NODES) dis[i0 + 1] = v1 > 0 ? rsqrtf((float)v1) : 0.f;
    int tsum = v0 + v1;
    s[threadIdx.x] = tsum;
    __syncthreads();
    for (int off = 1; off < 256; off <<= 1) {
        int val = (threadIdx.x >= off) ? s[threadIdx.x - off] : 0;
        __syncthreads();
        s[threadIdx.x] += val;
        __syncthreads();
    }
    int excl = s[threadIdx.x] - tsum;
    if (i0 < N_NODES) rp[i0] = excl;
    if (i0 + 1 < N_NODES) rp[i0 + 1] = excl + v0;
    if (threadIdx.x == 255) part[blockIdx.x] = s[255];
}

__global__ void k_scan2(int* __restrict__ part, int nb) {
    __shared__ int s[128];
    int t = threadIdx.x;
    int v = (t < nb) ? part[t] : 0;
    s[t] = v;
    __syncthreads();
    for (int off = 1; off < 128; off <<= 1) {
        int val = (t >= off) ? s[t - off] : 0;
        __syncthreads();
        s[t] += val;
        __syncthreads();
    }
    if (t < nb) part[t] = s[t] - v;  // exclusive
}

// scan phase 3; also seeds fill[i] = final rp[i] so scatter needs no rp load
__global__ void k_scan3(int* __restrict__ rp, const int* __restrict__ part,
                        int* __restrict__ fill) {
    int add = part[blockIdx.x];
    int i0 = blockIdx.x * 512 + 2 * threadIdx.x;
    if (i0 < N_NODES) {
        int v = rp[i0] + add;
        rp[i0] = v;
        fill[i0] = v;
    }
    if (i0 + 1 < N_NODES) {
        int v = rp[i0 + 1] + add;
        rp[i0 + 1] = v;
        fill[i0 + 1] = v;
    }
    if (blockIdx.x == 0 && threadIdx.x == 0) rp[N_NODES] = N_EDGES;
}

// packed CSR payload: (col, weight-bits). 1 edge/thread; position comes
// straight from atomicAdd on pre-seeded fill (no rp load in the chain).
__global__ void k_scatter(const int* __restrict__ row, const int* __restrict__ col,
                          const float* __restrict__ dis, int* __restrict__ fill,
                          int2* __restrict__ cw) {
    int e = blockIdx.x * 256 + threadIdx.x;
    if (e < N_EDGES) {
        int r = row[e], c = col[e];
        int pos = atomicAdd(&fill[r], 1);
        int2 v;
        v.x = c;
        v.y = __float_as_int(-dis[r] * dis[c]);
        cw[pos] = v;
    }
}

// ---------------- fused fp32->bf16 conversions (x + 3 transposed W) --------
#define NX (N_NODES * F_INN)
#define NW1 (3 * 128 * 192)
#define NW2 (3 * 192 * 192)
#define NW3 (3 * 192 * 128)
__global__ void k_convAll(const float* __restrict__ x, const float* __restrict__ W1,
                          const float* __restrict__ W2, const float* __restrict__ W3,
                          unsigned short* __restrict__ xb,
                          unsigned short* __restrict__ Wt1,
                          unsigned short* __restrict__ Wt2,
                          unsigned short* __restrict__ Wt3) {
    int idx = blockIdx.x * 256 + threadIdx.x;
    if (idx < NX) {
        xb[idx] = f2bf(x[idx]);
        return;
    }
    idx -= NX;
    if (idx < NW1) {  // W1[j][k][n] -> Wt1[j][n][k], Fin=128, Fout=192
        int per = 128 * 192;
        int j = idx / per, r = idx - j * per;
        int k = r / 192, n = r - k * 192;
        Wt1[j * per + n * 128 + k] = f2bf(W1[idx]);
        return;
    }
    idx -= NW1;
    if (idx < NW2) {  // Fin=192, Fout=192
        int per = 192 * 192;
        int j = idx / per, r = idx - j * per;
        int k = r / 192, n = r - k * 192;
        Wt2[j * per + n * 192 + k] = f2bf(W2[idx]);
        return;
    }
    idx -= NW2;
    if (idx < NW3) {  // Fin=192, Fout=128
        int per = 192 * 128;
        int j = idx / per, r = idx - j * per;
        int k = r / 128, n = r - k * 128;
        Wt3[j * per + n * 192 + k] = f2bf(W3[idx]);
    }
}

// ---------------- SpMV (bf16 in/out, fp32 accum) ----------------
// y = alpha*(L_hat@h) + beta*z. One wave per row. Lane l owns feats
// {2l, 2l+1} (packed uint gather) + feat 128+l (ushort) for F=192.
// Edge metadata (rp bounds, col, w) is wave-uniform -> readfirstlane
// scalarizes address math + weight operand; edge loop unrolled x8 so
// 8 (16 for F=192) gather latency chains overlap.
template <int F>
__global__ void k_spmv(const int* __restrict__ rp, const int2* __restrict__ cw,
                       const unsigned short* __restrict__ h,
                       const unsigned short* __restrict__ z, float alpha, float beta,
                       unsigned short* __restrict__ y) {
    constexpr bool EX = (F > 128);
    constexpr int FU = F / 2;  // uints per row
    int wave = threadIdx.x >> 6;
    int lane = threadIdx.x & 63;
    int r = blockIdx.x * 4 + wave;
    if (r >= N_NODES) return;
    int e0 = __builtin_amdgcn_readfirstlane(rp[r]);
    int e1 = __builtin_amdgcn_readfirstlane(rp[r + 1]);
    const unsigned int* hu = (const unsigned int*)h;
    float a0 = 0.f, a1 = 0.f, a2 = 0.f;
    int e = e0;
    for (; e + 8 <= e1; e += 8) {
        int colv[8];
        float wv[8];
#pragma unroll
        for (int u = 0; u < 8; u++) {
            int2 p = cw[e + u];
            colv[u] = __builtin_amdgcn_readfirstlane(p.x);
            wv[u] = __uint_as_float(__builtin_amdgcn_readfirstlane(p.y));
        }
        unsigned int g[8];
        unsigned short s[8];
#pragma unroll
        for (int u = 0; u < 8; u++) {
            g[u] = hu[colv[u] * FU + lane];
            if constexpr (EX) s[u] = h[colv[u] * F + 128 + lane];
        }
#pragma unroll
        for (int u = 0; u < 8; u++) {
            a0 += wv[u] * bf2f((unsigned short)g[u]);
            a1 += wv[u] * bf2f((unsigned short)(g[u] >> 16));
            if constexpr (EX) a2 += wv[u] * bf2f(s[u]);
        }
    }
    for (; e + 4 <= e1; e += 4) {
        int colv[4];
        float wv[4];
#pragma unroll
        for (int u = 0; u < 4; u++) {
            int2 p = cw[e + u];
            colv[u] = __builtin_amdgcn_readfirstlane(p.x);
            wv[u] = __uint_as_float(__builtin_amdgcn_readfirstlane(p.y));
        }
        unsigned int g[4];
        unsigned short s[4];
#pragma unroll
        for (int u = 0; u < 4; u++) {
            g[u] = hu[colv[u] * FU + lane];
            if constexpr (EX) s[u] = h[colv[u] * F + 128 + lane];
        }
#pragma unroll
        for (int u = 0; u < 4; u++) {
            a0 += wv[u] * bf2f((unsigned short)g[u]);
            a1 += wv[u] * bf2f((unsigned short)(g[u] >> 16));
            if constexpr (EX) a2 += wv[u] * bf2f(s[u]);
        }
    }
    for (; e < e1; e++) {
        int2 p = cw[e];
        int c = __builtin_amdgcn_readfirstlane(p.x);
        float w = __uint_as_float(__builtin_amdgcn_readfirstlane(p.y));
        unsigned int g = hu[c * FU + lane];
        a0 += w * bf2f((unsigned short)g);
        a1 += w * bf2f((unsigned short)(g >> 16));
        if constexpr (EX) a2 += w * bf2f(h[c * F + 128 + lane]);
    }
    float v0 = alpha * a0, v1 = alpha * a1, v2 = alpha * a2;
    if (beta != 0.f) {
        unsigned int zg = ((const unsigned int*)z)[r * FU + lane];
        v0 += beta * bf2f((unsigned short)zg);
        v1 += beta * bf2f((unsigned short)(zg >> 16));
        if constexpr (EX) v2 += beta * bf2f(z[r * F + 128 + lane]);
    }
    ((unsigned int*)y)[r * FU + lane] =
        (unsigned int)f2bf(v0) | ((unsigned int)f2bf(v1) << 16);
    if constexpr (EX) y[r * F + 128 + lane] = f2bf(v2);
}

// ---------------- fused 3-matrix bf16 MFMA GEMM ----------------
// C = A0@W[0]+A1@W[1]+A2@W[2]+bias, A row-major [M][Fin] bf16,
// Wt pre-transposed [3][Fout][Fin] bf16, C bf16 [M][Fout].
// Block: 256 thr = 4 waves; tile M=128 x N=64; wave = 32 rows x 64 cols
// = 2x4 grid of 16x16x32 MFMAs. LDS stride 40 shorts breaks pow-2 conflicts.
__global__ __launch_bounds__(256) void k_gemm3(
    const unsigned short* __restrict__ A0, const unsigned short* __restrict__ A1,
    const unsigned short* __restrict__ A2, const unsigned short* __restrict__ Wt,
    const float* __restrict__ bias, unsigned short* __restrict__ C, int Fin,
    int Fout) {
    __shared__ unsigned short As[128 * 40];
    __shared__ unsigned short Bs[64 * 40];
    int t = threadIdx.x;
    int w = t >> 6;
    int lane = t & 63;
    int ml = lane & 15;
    int quad = lane >> 4;
    int mBase = blockIdx.x * 128;
    int nBase = blockIdx.y * 64;
    int per = Fin * Fout;

    f32x4 acc[2][4];
#pragma unroll
    for (int i = 0; i < 2; i++)
#pragma unroll
        for (int jn = 0; jn < 4; jn++) acc[i][jn] = (f32x4){0.f, 0.f, 0.f, 0.f};

    int srow = t >> 2;   // 0..63
    int schunk = t & 3;  // 16B chunk within 32-k slab
    int nChunks = (3 * Fin) >> 5;

    for (int ch = 0; ch < nChunks; ch++) {
        int kg = ch << 5;
        int j = kg / Fin;
        int kk = kg - j * Fin;
        const unsigned short* Aj = (j == 0) ? A0 : (j == 1) ? A1 : A2;
        if (ch > 0) __syncthreads();
#pragma unroll
        for (int pass = 0; pass < 2; pass++) {
            int row = srow + pass * 64;
            int gm = mBase + row;
            uint4 v = {0u, 0u, 0u, 0u};
            if (gm < N_NODES)
                v = *(const uint4*)(Aj + (size_t)gm * Fin + kk + schunk * 8);
            *(uint4*)&As[row * 40 + schunk * 8] = v;
        }
        {
            const unsigned short* src =
                Wt + (size_t)j * per + (size_t)(nBase + srow) * Fin + kk + schunk * 8;
            *(uint4*)&Bs[srow * 40 + schunk * 8] = *(const uint4*)src;
        }
        __syncthreads();

        short8 afr[2], bfr[4];
#pragma unroll
        for (int i = 0; i < 2; i++)
            afr[i] = *(const short8*)&As[(w * 32 + i * 16 + ml) * 40 + quad * 8];
#pragma unroll
        for (int jn = 0; jn < 4; jn++)
            bfr[jn] = *(const short8*)&Bs[(jn * 16 + ml) * 40 + quad * 8];
#pragma unroll
        for (int i = 0; i < 2; i++)
#pragma unroll
            for (int jn = 0; jn < 4; jn++)
                acc[i][jn] = __builtin_amdgcn_mfma_f32_16x16x32_bf16(
                    afr[i], bfr[jn], acc[i][jn], 0, 0, 0);
    }

    float biasv[4];
#pragma unroll
    for (int jn = 0; jn < 4; jn++) biasv[jn] = bias[nBase + jn * 16 + ml];

#pragma unroll
    for (int i = 0; i < 2; i++) {
#pragma unroll
        for (int r = 0; r < 4; r++) {
            int m = mBase + w * 32 + i * 16 + quad * 4 + r;
            if (m < N_NODES) {
                unsigned short* cp = C + (size_t)m * Fout + nBase + ml;
#pragma unroll
                for (int jn = 0; jn < 4; jn++)
                    cp[jn * 16] = f2bf(acc[i][jn][r] + biasv[jn]);
            }
        }
    }
}

// ---------------- pooling: chunked partial sums + atomics ----------------
__global__ void k_pool_partial(const unsigned short* __restrict__ h,
                               const int* __restrict__ batch,
                               float* __restrict__ psum, int* __restrict__ pcnt) {
    int f = threadIdx.x;  // 128
    int n0 = blockIdx.x * POOL_CHUNK;
    int n1 = n0 + POOL_CHUNK;
    if (n1 > N_NODES) n1 = N_NODES;
    if (n0 >= N_NODES) return;
    int curg = batch[n0];
    float acc = 0.f;
    int run = 0;
    for (int n = n0; n < n1; n++) {
        int g = batch[n];
        if (g != curg) {
            atomicAdd(&psum[curg * F_OUTT + f], acc);
            if (f == 0) atomicAdd(&pcnt[curg], run);
            acc = 0.f;
            run = 0;
            curg = g;
        }
        acc += bf2f(h[(size_t)n * F_OUTT + f]);
        run++;
    }
    atomicAdd(&psum[curg * F_OUTT + f], acc);
    if (f == 0) atomicAdd(&pcnt[curg], run);
}

__global__ void k_head(const float* __restrict__ psum, const int* __restrict__ pcnt,
                       const float* __restrict__ fcw, const float* __restrict__ fcb,
                       float* __restrict__ out) {
    int g = blockIdx.x;
    int c = threadIdx.x;  // 64 threads, lanes >= N_CLS idle
    __shared__ float sl[N_CLS];
    float inv = 1.f / fmaxf((float)pcnt[g], 1.f);
    float l = 0.f;
    if (c < N_CLS) {
        l = fcb[c];
        for (int k = 0; k < F_OUTT; k++)
            l += psum[g * F_OUTT + k] * inv * fcw[k * N_CLS + c];
        sl[c] = l;
    }
    __syncthreads();
    if (c < N_CLS) {
        float m = -1e30f;
        for (int i = 0; i < N_CLS; i++) m = fmaxf(m, sl[i]);
        float s = 0.f;
        for (int i = 0; i < N_CLS; i++) s += expf(sl[i] - m);
        out[g * N_CLS + c] = l - m - logf(s);
    }
}

extern "C" void kernel_launch(void* const* d_in, const int* in_sizes, int n_in,
                              void* d_out, int out_size, void* d_ws, size_t ws_size,
                              hipStream_t stream) {
    const float* x = (const float*)d_in[0];
    const int* ei = (const int*)d_in[1];
    const int* batch = (const int*)d_in[2];
    const float* W1 = (const float*)d_in[3];
    const float* b1 = (const float*)d_in[4];
    const float* W2 = (const float*)d_in[5];
    const float* b2 = (const float*)d_in[6];
    const float* W3 = (const float*)d_in[7];
    const float* b3 = (const float*)d_in[8];
    const float* fcw = (const float*)d_in[9];
    const float* fcb = (const float*)d_in[10];
    float* out = (float*)d_out;
    const int* row = ei;
    const int* col = ei + N_EDGES;

    char* p = (char*)d_ws;
    auto carve = [&](size_t bytes) {
        char* q = p;
        p += (bytes + 255) & ~(size_t)255;
        return q;
    };
    int* cnt = (int*)carve(N_NODES * 4);
    int* fill = (int*)carve(N_NODES * 4);
    float* dis = (float*)carve(N_NODES * 4);
    int* rp = (int*)carve((N_NODES + 1) * 4);
    int* part = (int*)carve(128 * 4);
    int2* cw = (int2*)carve((size_t)N_EDGES * 8);
    unsigned short* xb = (unsigned short*)carve((size_t)N_NODES * F_INN * 2);
    size_t hbytes = (size_t)N_NODES * 192 * 2;
    unsigned short* bufA = (unsigned short*)carve(hbytes);
    unsigned short* bufB = (unsigned short*)carve(hbytes);
    unsigned short* bufC = (unsigned short*)carve(hbytes);
    unsigned short* bufD = (unsigned short*)carve(hbytes);
    unsigned short* Wt1 = (unsigned short*)carve(NW1 * 2);
    unsigned short* Wt2 = (unsigned short*)carve(NW2 * 2);
    unsigned short* Wt3 = (unsigned short*)carve(NW3 * 2);
    float* psum = (float*)carve(N_GRAPHS * F_OUTT * 4);
    int* pcnt = (int*)carve(N_GRAPHS * 4);

    hipMemsetAsync(cnt, 0, N_NODES * 4, stream);
    hipMemsetAsync(psum, 0, N_GRAPHS * F_OUTT * 4, stream);
    hipMemsetAsync(pcnt, 0, N_GRAPHS * 4, stream);

    k_deg<<<(N_EDGES + 255) / 256, 256, 0, stream>>>(row, cnt);
    int nb = (N_NODES + 511) / 512;  // 98
    k_scan1<<<nb, 256, 0, stream>>>(cnt, rp, part, dis);
    k_scan2<<<1, 128, 0, stream>>>(part, nb);
    k_scan3<<<nb, 256, 0, stream>>>(rp, part, fill);
    k_scatter<<<(N_EDGES + 255) / 256, 256, 0, stream>>>(row, col, dis, fill, cw);

    {
        int tot = NX + NW1 + NW2 + NW3;
        k_convAll<<<(tot + 255) / 256, 256, 0, stream>>>(x, W1, W2, W3, xb, Wt1, Wt2,
                                                         Wt3);
    }

    const int spmvGrid = (N_NODES + 3) / 4;

    // Layer 1: in=xb (128) -> out=bufA (192)
    k_spmv<128><<<spmvGrid, 256, 0, stream>>>(rp, cw, xb, xb, 1.f, 0.f, bufB);
    k_spmv<128><<<spmvGrid, 256, 0, stream>>>(rp, cw, bufB, xb, 2.f, -1.f, bufC);
    {
        dim3 g((N_NODES + 127) / 128, 192 / 64);
        k_gemm3<<<g, 256, 0, stream>>>(xb, bufB, bufC, Wt1, b1, bufA, 128, 192);
    }
    // Layer 2: in=bufA (192) -> out=bufD (192)
    k_spmv<192><<<spmvGrid, 256, 0, stream>>>(rp, cw, bufA, bufA, 1.f, 0.f, bufB);
    k_spmv<192><<<spmvGrid, 256, 0, stream>>>(rp, cw, bufB, bufA, 2.f, -1.f, bufC);
    {
        dim3 g((N_NODES + 127) / 128, 192 / 64);
        k_gemm3<<<g, 256, 0, stream>>>(bufA, bufB, bufC, Wt2, b2, bufD, 192, 192);
    }
    // Layer 3: in=bufD (192) -> out=bufA (128)
    k_spmv<192><<<spmvGrid, 256, 0, stream>>>(rp, cw, bufD, bufD, 1.f, 0.f, bufB);
    k_spmv<192><<<spmvGrid, 256, 0, stream>>>(rp, cw, bufB, bufD, 2.f, -1.f, bufC);
    {
        dim3 g((N_NODES + 127) / 128, 128 / 64);
        k_gemm3<<<g, 256, 0, stream>>>(bufD, bufB, bufC, Wt3, b3, bufA, 192, 128);
    }

    k_pool_partial<<<(N_NODES + POOL_CHUNK - 1) / POOL_CHUNK, F_OUTT, 0, stream>>>(
        bufA, batch, psum, pcnt);
    k_head<<<N_GRAPHS, 64, 0, stream>>>(psum, pcnt, fcw, fcb, out);
}

// Round 8
// 515.586 us; speedup vs baseline: 1.0848x; 1.0442x over previous
//
#include <hip/hip_runtime.h>
#include <math.h>

#define N_NODES 50000
#define N_EDGES 800000
#define N_GRAPHS 64
#define F_INN 128
#define F_HID 192
#define F_OUTT 128
#define N_CLS 10
#define POOL_CHUNK 128

typedef short short8 __attribute__((ext_vector_type(8)));
typedef float f32x4 __attribute__((ext_vector_type(4)));

static __device__ inline unsigned short f2bf(float f) {
    unsigned int u = __float_as_uint(f);
    unsigned int r = (u + 0x7FFFu + ((u >> 16) & 1u)) >> 16;  // RNE
    return (unsigned short)r;
}
static __device__ inline float bf2f(unsigned short h) {
    return __uint_as_float(((unsigned int)h) << 16);
}

// ---------------- CSR build ----------------
// k_deg also records each edge's rank within its row (atomic return is free
// here); scatter then needs NO atomic. 1 edge/thread (TLP > ILP for random
// atomics — round-6 lesson).
__global__ void k_deg(const int* __restrict__ row, int* __restrict__ cnt,
                      int* __restrict__ rank) {
    int e = blockIdx.x * 256 + threadIdx.x;
    if (e < N_EDGES) rank[e] = atomicAdd(&cnt[row[e]], 1);
}

// scan phase 1 + fused dis = rsqrt(deg)
__global__ void k_scan1(const int* __restrict__ cnt, int* __restrict__ rp,
                        int* __restrict__ part, float* __restrict__ dis) {
    __shared__ int s[256];
    int base = blockIdx.x * 512;
    int i0 = base + 2 * threadIdx.x;
    int v0 = (i0 < N_NODES) ? cnt[i0] : 0;
    int v1 = (i0 + 1 < N_NODES) ? cnt[i0 + 1] : 0;
    if (i0 < N_NODES) dis[i0] = v0 > 0 ? rsqrtf((float)v0) : 0.f;
    if (i0 + 1 < N_NODES) dis[i0 + 1] = v1 > 0 ? rsqrtf((float)v1) : 0.f;
    int tsum = v0 + v1;
    s[threadIdx.x] = tsum;
    __syncthreads();
    for (int off = 1; off < 256; off <<= 1) {
        int val = (threadIdx.x >= off) ? s[threadIdx.x - off] : 0;
        __syncthreads();
        s[threadIdx.x] += val;
        __syncthreads();
    }
    int excl = s[threadIdx.x] - tsum;
    if (i0 < N_NODES) rp[i0] = excl;
    if (i0 + 1 < N_NODES) rp[i0 + 1] = excl + v0;
    if (threadIdx.x == 255) part[blockIdx.x] = s[255];
}

__global__ void k_scan2(int* __restrict__ part, int nb) {
    __shared__ int s[128];
    int t = threadIdx.x;
    int v = (t < nb) ? part[t] : 0;
    s[t] = v;
    __syncthreads();
    for (int off = 1; off < 128; off <<= 1) {
        int val = (t >= off) ? s[t - off] : 0;
        __syncthreads();
        s[t] += val;
        __syncthreads();
    }
    if (t < nb) part[t] = s[t] - v;  // exclusive
}

__global__ void k_scan3(int* __restrict__ rp, const int* __restrict__ part) {
    int add = part[blockIdx.x];
    int i0 = blockIdx.x * 512 + 2 * threadIdx.x;
    if (i0 < N_NODES) rp[i0] += add;
    if (i0 + 1 < N_NODES) rp[i0 + 1] += add;
    if (blockIdx.x == 0 && threadIdx.x == 0) rp[N_NODES] = N_EDGES;
}

// packed CSR payload: (col, weight-bits). Atomic-free: pos = rp[r] + rank[e].
__global__ void k_scatter(const int* __restrict__ row, const int* __restrict__ col,
                          const float* __restrict__ dis, const int* __restrict__ rp,
                          const int* __restrict__ rank, int2* __restrict__ cw) {
    int e = blockIdx.x * 256 + threadIdx.x;
    if (e < N_EDGES) {
        int r = row[e], c = col[e];
        int pos = rp[r] + rank[e];
        int2 v;
        v.x = c;
        v.y = __float_as_int(-dis[r] * dis[c]);
        cw[pos] = v;
    }
}

// ---------------- fused fp32->bf16 conversions (x + 3 transposed W) --------
#define NX (N_NODES * F_INN)
#define NW1 (3 * 128 * 192)
#define NW2 (3 * 192 * 192)
#define NW3 (3 * 192 * 128)
__global__ void k_convAll(const float* __restrict__ x, const float* __restrict__ W1,
                          const float* __restrict__ W2, const float* __restrict__ W3,
                          unsigned short* __restrict__ xb,
                          unsigned short* __restrict__ Wt1,
                          unsigned short* __restrict__ Wt2,
                          unsigned short* __restrict__ Wt3) {
    int idx = blockIdx.x * 256 + threadIdx.x;
    if (idx < NX) {
        xb[idx] = f2bf(x[idx]);
        return;
    }
    idx -= NX;
    if (idx < NW1) {  // W1[j][k][n] -> Wt1[j][n][k], Fin=128, Fout=192
        int per = 128 * 192;
        int j = idx / per, r = idx - j * per;
        int k = r / 192, n = r - k * 192;
        Wt1[j * per + n * 128 + k] = f2bf(W1[idx]);
        return;
    }
    idx -= NW1;
    if (idx < NW2) {  // Fin=192, Fout=192
        int per = 192 * 192;
        int j = idx / per, r = idx - j * per;
        int k = r / 192, n = r - k * 192;
        Wt2[j * per + n * 192 + k] = f2bf(W2[idx]);
        return;
    }
    idx -= NW2;
    if (idx < NW3) {  // Fin=192, Fout=128
        int per = 192 * 128;
        int j = idx / per, r = idx - j * per;
        int k = r / 128, n = r - k * 128;
        Wt3[j * per + n * 192 + k] = f2bf(W3[idx]);
    }
}

// ---------------- SpMV (bf16 in/out, fp32 accum) ----------------
// y = alpha*(L_hat@h) + beta*z. One wave per row. Lane l owns feats
// {2l, 2l+1} (packed uint gather) + feat 128+l (ushort) for F=192.
// Edge metadata is wave-uniform -> readfirstlane scalarizes it; edge loop
// unrolled x16 (avg degree = 16) so 16 (32 for F=192) gathers fly together.
template <int F>
__global__ void k_spmv(const int* __restrict__ rp, const int2* __restrict__ cw,
                       const unsigned short* __restrict__ h,
                       const unsigned short* __restrict__ z, float alpha, float beta,
                       unsigned short* __restrict__ y) {
    constexpr bool EX = (F > 128);
    constexpr int FU = F / 2;  // uints per row
    int wave = threadIdx.x >> 6;
    int lane = threadIdx.x & 63;
    int r = blockIdx.x * 4 + wave;
    if (r >= N_NODES) return;
    int e0 = __builtin_amdgcn_readfirstlane(rp[r]);
    int e1 = __builtin_amdgcn_readfirstlane(rp[r + 1]);
    const unsigned int* hu = (const unsigned int*)h;
    float a0 = 0.f, a1 = 0.f, a2 = 0.f;
    int e = e0;
    for (; e + 16 <= e1; e += 16) {
        int colv[16];
        float wv[16];
#pragma unroll
        for (int u = 0; u < 16; u++) {
            int2 p = cw[e + u];
            colv[u] = __builtin_amdgcn_readfirstlane(p.x);
            wv[u] = __uint_as_float(__builtin_amdgcn_readfirstlane(p.y));
        }
        unsigned int g[16];
        unsigned short s[16];
#pragma unroll
        for (int u = 0; u < 16; u++) {
            g[u] = hu[colv[u] * FU + lane];
            if constexpr (EX) s[u] = h[colv[u] * F + 128 + lane];
        }
#pragma unroll
        for (int u = 0; u < 16; u++) {
            a0 += wv[u] * bf2f((unsigned short)g[u]);
            a1 += wv[u] * bf2f((unsigned short)(g[u] >> 16));
            if constexpr (EX) a2 += wv[u] * bf2f(s[u]);
        }
    }
    for (; e + 8 <= e1; e += 8) {
        int colv[8];
        float wv[8];
#pragma unroll
        for (int u = 0; u < 8; u++) {
            int2 p = cw[e + u];
            colv[u] = __builtin_amdgcn_readfirstlane(p.x);
            wv[u] = __uint_as_float(__builtin_amdgcn_readfirstlane(p.y));
        }
        unsigned int g[8];
        unsigned short s[8];
#pragma unroll
        for (int u = 0; u < 8; u++) {
            g[u] = hu[colv[u] * FU + lane];
            if constexpr (EX) s[u] = h[colv[u] * F + 128 + lane];
        }
#pragma unroll
        for (int u = 0; u < 8; u++) {
            a0 += wv[u] * bf2f((unsigned short)g[u]);
            a1 += wv[u] * bf2f((unsigned short)(g[u] >> 16));
            if constexpr (EX) a2 += wv[u] * bf2f(s[u]);
        }
    }
    for (; e + 4 <= e1; e += 4) {
        int colv[4];
        float wv[4];
#pragma unroll
        for (int u = 0; u < 4; u++) {
            int2 p = cw[e + u];
            colv[u] = __builtin_amdgcn_readfirstlane(p.x);
            wv[u] = __uint_as_float(__builtin_amdgcn_readfirstlane(p.y));
        }
        unsigned int g[4];
        unsigned short s[4];
#pragma unroll
        for (int u = 0; u < 4; u++) {
            g[u] = hu[colv[u] * FU + lane];
            if constexpr (EX) s[u] = h[colv[u] * F + 128 + lane];
        }
#pragma unroll
        for (int u = 0; u < 4; u++) {
            a0 += wv[u] * bf2f((unsigned short)g[u]);
            a1 += wv[u] * bf2f((unsigned short)(g[u] >> 16));
            if constexpr (EX) a2 += wv[u] * bf2f(s[u]);
        }
    }
    for (; e < e1; e++) {
        int2 p = cw[e];
        int c = __builtin_amdgcn_readfirstlane(p.x);
        float w = __uint_as_float(__builtin_amdgcn_readfirstlane(p.y));
        unsigned int g = hu[c * FU + lane];
        a0 += w * bf2f((unsigned short)g);
        a1 += w * bf2f((unsigned short)(g >> 16));
        if constexpr (EX) a2 += w * bf2f(h[c * F + 128 + lane]);
    }
    float v0 = alpha * a0, v1 = alpha * a1, v2 = alpha * a2;
    if (beta != 0.f) {
        unsigned int zg = ((const unsigned int*)z)[r * FU + lane];
        v0 += beta * bf2f((unsigned short)zg);
        v1 += beta * bf2f((unsigned short)(zg >> 16));
        if constexpr (EX) v2 += beta * bf2f(z[r * F + 128 + lane]);
    }
    ((unsigned int*)y)[r * FU + lane] =
        (unsigned int)f2bf(v0) | ((unsigned int)f2bf(v1) << 16);
    if constexpr (EX) y[r * F + 128 + lane] = f2bf(v2);
}

// ---------------- fused 3-matrix bf16 MFMA GEMM ----------------
// C = A0@W[0]+A1@W[1]+A2@W[2]+bias, A row-major [M][Fin] bf16,
// Wt pre-transposed [3][Fout][Fin] bf16, C bf16 [M][Fout].
// Block: 256 thr = 4 waves; tile M=128 x N=64; wave = 32 rows x 64 cols
// = 2x4 grid of 16x16x32 MFMAs. LDS stride 40 shorts breaks pow-2 conflicts.
__global__ __launch_bounds__(256) void k_gemm3(
    const unsigned short* __restrict__ A0, const unsigned short* __restrict__ A1,
    const unsigned short* __restrict__ A2, const unsigned short* __restrict__ Wt,
    const float* __restrict__ bias, unsigned short* __restrict__ C, int Fin,
    int Fout) {
    __shared__ unsigned short As[128 * 40];
    __shared__ unsigned short Bs[64 * 40];
    int t = threadIdx.x;
    int w = t >> 6;
    int lane = t & 63;
    int ml = lane & 15;
    int quad = lane >> 4;
    int mBase = blockIdx.x * 128;
    int nBase = blockIdx.y * 64;
    int per = Fin * Fout;

    f32x4 acc[2][4];
#pragma unroll
    for (int i = 0; i < 2; i++)
#pragma unroll
        for (int jn = 0; jn < 4; jn++) acc[i][jn] = (f32x4){0.f, 0.f, 0.f, 0.f};

    int srow = t >> 2;   // 0..63
    int schunk = t & 3;  // 16B chunk within 32-k slab
    int nChunks = (3 * Fin) >> 5;

    for (int ch = 0; ch < nChunks; ch++) {
        int kg = ch << 5;
        int j = kg / Fin;
        int kk = kg - j * Fin;
        const unsigned short* Aj = (j == 0) ? A0 : (j == 1) ? A1 : A2;
        if (ch > 0) __syncthreads();
#pragma unroll
        for (int pass = 0; pass < 2; pass++) {
            int row = srow + pass * 64;
            int gm = mBase + row;
            uint4 v = {0u, 0u, 0u, 0u};
            if (gm < N_NODES)
                v = *(const uint4*)(Aj + (size_t)gm * Fin + kk + schunk * 8);
            *(uint4*)&As[row * 40 + schunk * 8] = v;
        }
        {
            const unsigned short* src =
                Wt + (size_t)j * per + (size_t)(nBase + srow) * Fin + kk + schunk * 8;
            *(uint4*)&Bs[srow * 40 + schunk * 8] = *(const uint4*)src;
        }
        __syncthreads();

        short8 afr[2], bfr[4];
#pragma unroll
        for (int i = 0; i < 2; i++)
            afr[i] = *(const short8*)&As[(w * 32 + i * 16 + ml) * 40 + quad * 8];
#pragma unroll
        for (int jn = 0; jn < 4; jn++)
            bfr[jn] = *(const short8*)&Bs[(jn * 16 + ml) * 40 + quad * 8];
#pragma unroll
        for (int i = 0; i < 2; i++)
#pragma unroll
            for (int jn = 0; jn < 4; jn++)
                acc[i][jn] = __builtin_amdgcn_mfma_f32_16x16x32_bf16(
                    afr[i], bfr[jn], acc[i][jn], 0, 0, 0);
    }

    float biasv[4];
#pragma unroll
    for (int jn = 0; jn < 4; jn++) biasv[jn] = bias[nBase + jn * 16 + ml];

#pragma unroll
    for (int i = 0; i < 2; i++) {
#pragma unroll
        for (int r = 0; r < 4; r++) {
            int m = mBase + w * 32 + i * 16 + quad * 4 + r;
            if (m < N_NODES) {
                unsigned short* cp = C + (size_t)m * Fout + nBase + ml;
#pragma unroll
                for (int jn = 0; jn < 4; jn++)
                    cp[jn * 16] = f2bf(acc[i][jn][r] + biasv[jn]);
            }
        }
    }
}

// ---------------- pooling: chunked partial sums + atomics ----------------
__global__ void k_pool_partial(const unsigned short* __restrict__ h,
                               const int* __restrict__ batch,
                               float* __restrict__ psum, int* __restrict__ pcnt) {
    int f = threadIdx.x;  // 128
    int n0 = blockIdx.x * POOL_CHUNK;
    int n1 = n0 + POOL_CHUNK;
    if (n1 > N_NODES) n1 = N_NODES;
    if (n0 >= N_NODES) return;
    int curg = batch[n0];
    float acc = 0.f;
    int run = 0;
    for (int n = n0; n < n1; n++) {
        int g = batch[n];
        if (g != curg) {
            atomicAdd(&psum[curg * F_OUTT + f], acc);
            if (f == 0) atomicAdd(&pcnt[curg], run);
            acc = 0.f;
            run = 0;
            curg = g;
        }
        acc += bf2f(h[(size_t)n * F_OUTT + f]);
        run++;
    }
    atomicAdd(&psum[curg * F_OUTT + f], acc);
    if (f == 0) atomicAdd(&pcnt[curg], run);
}

__global__ void k_head(const float* __restrict__ psum, const int* __restrict__ pcnt,
                       const float* __restrict__ fcw, const float* __restrict__ fcb,
                       float* __restrict__ out) {
    int g = blockIdx.x;
    int c = threadIdx.x;  // 64 threads, lanes >= N_CLS idle
    __shared__ float sl[N_CLS];
    float inv = 1.f / fmaxf((float)pcnt[g], 1.f);
    float l = 0.f;
    if (c < N_CLS) {
        l = fcb[c];
        for (int k = 0; k < F_OUTT; k++)
            l += psum[g * F_OUTT + k] * inv * fcw[k * N_CLS + c];
        sl[c] = l;
    }
    __syncthreads();
    if (c < N_CLS) {
        float m = -1e30f;
        for (int i = 0; i < N_CLS; i++) m = fmaxf(m, sl[i]);
        float s = 0.f;
        for (int i = 0; i < N_CLS; i++) s += expf(sl[i] - m);
        out[g * N_CLS + c] = l - m - logf(s);
    }
}

extern "C" void kernel_launch(void* const* d_in, const int* in_sizes, int n_in,
                              void* d_out, int out_size, void* d_ws, size_t ws_size,
                              hipStream_t stream) {
    const float* x = (const float*)d_in[0];
    const int* ei = (const int*)d_in[1];
    const int* batch = (const int*)d_in[2];
    const float* W1 = (const float*)d_in[3];
    const float* b1 = (const float*)d_in[4];
    const float* W2 = (const float*)d_in[5];
    const float* b2 = (const float*)d_in[6];
    const float* W3 = (const float*)d_in[7];
    const float* b3 = (const float*)d_in[8];
    const float* fcw = (const float*)d_in[9];
    const float* fcb = (const float*)d_in[10];
    float* out = (float*)d_out;
    const int* row = ei;
    const int* col = ei + N_EDGES;

    char* p = (char*)d_ws;
    auto carve = [&](size_t bytes) {
        char* q = p;
        p += (bytes + 255) & ~(size_t)255;
        return q;
    };
    int* cnt = (int*)carve(N_NODES * 4);
    int* rank = (int*)carve((size_t)N_EDGES * 4);
    float* dis = (float*)carve(N_NODES * 4);
    int* rp = (int*)carve((N_NODES + 1) * 4);
    int* part = (int*)carve(128 * 4);
    int2* cw = (int2*)carve((size_t)N_EDGES * 8);
    unsigned short* xb = (unsigned short*)carve((size_t)N_NODES * F_INN * 2);
    size_t hbytes = (size_t)N_NODES * 192 * 2;
    unsigned short* bufA = (unsigned short*)carve(hbytes);
    unsigned short* bufB = (unsigned short*)carve(hbytes);
    unsigned short* bufC = (unsigned short*)carve(hbytes);
    unsigned short* bufD = (unsigned short*)carve(hbytes);
    unsigned short* Wt1 = (unsigned short*)carve(NW1 * 2);
    unsigned short* Wt2 = (unsigned short*)carve(NW2 * 2);
    unsigned short* Wt3 = (unsigned short*)carve(NW3 * 2);
    float* psum = (float*)carve(N_GRAPHS * F_OUTT * 4);
    int* pcnt = (int*)carve(N_GRAPHS * 4);

    hipMemsetAsync(cnt, 0, N_NODES * 4, stream);
    hipMemsetAsync(psum, 0, N_GRAPHS * F_OUTT * 4, stream);
    hipMemsetAsync(pcnt, 0, N_GRAPHS * 4, stream);

    k_deg<<<(N_EDGES + 255) / 256, 256, 0, stream>>>(row, cnt, rank);
    int nb = (N_NODES + 511) / 512;  // 98
    k_scan1<<<nb, 256, 0, stream>>>(cnt, rp, part, dis);
    k_scan2<<<1, 128, 0, stream>>>(part, nb);
    k_scan3<<<nb, 256, 0, stream>>>(rp, part);
    k_scatter<<<(N_EDGES + 255) / 256, 256, 0, stream>>>(row, col, dis, rp, rank, cw);

    {
        int tot = NX + NW1 + NW2 + NW3;
        k_convAll<<<(tot + 255) / 256, 256, 0, stream>>>(x, W1, W2, W3, xb, Wt1, Wt2,
                                                         Wt3);
    }

    const int spmvGrid = (N_NODES + 3) / 4;

    // Layer 1: in=xb (128) -> out=bufA (192)
    k_spmv<128><<<spmvGrid, 256, 0, stream>>>(rp, cw, xb, xb, 1.f, 0.f, bufB);
    k_spmv<128><<<spmvGrid, 256, 0, stream>>>(rp, cw, bufB, xb, 2.f, -1.f, bufC);
    {
        dim3 g((N_NODES + 127) / 128, 192 / 64);
        k_gemm3<<<g, 256, 0, stream>>>(xb, bufB, bufC, Wt1, b1, bufA, 128, 192);
    }
    // Layer 2: in=bufA (192) -> out=bufD (192)
    k_spmv<192><<<spmvGrid, 256, 0, stream>>>(rp, cw, bufA, bufA, 1.f, 0.f, bufB);
    k_spmv<192><<<spmvGrid, 256, 0, stream>>>(rp, cw, bufB, bufA, 2.f, -1.f, bufC);
    {
        dim3 g((N_NODES + 127) / 128, 192 / 64);
        k_gemm3<<<g, 256, 0, stream>>>(bufA, bufB, bufC, Wt2, b2, bufD, 192, 192);
    }
    // Layer 3: in=bufD (192) -> out=bufA (128)
    k_spmv<192><<<spmvGrid, 256, 0, stream>>>(rp, cw, bufD, bufD, 1.f, 0.f, bufB);
    k_spmv<192><<<spmvGrid, 256, 0, stream>>>(rp, cw, bufB, bufD, 2.f, -1.f, bufC);
    {
        dim3 g((N_NODES + 127) / 128, 128 / 64);
        k_gemm3<<<g, 256, 0, stream>>>(bufD, bufB, bufC, Wt3, b3, bufA, 192, 128);
    }

    k_pool_partial<<<(N_NODES + POOL_CHUNK - 1) / POOL_CHUNK, F_OUTT, 0, stream>>>(
        bufA, batch, psum, pcnt);
    k_head<<<N_GRAPHS, 64, 0, stream>>>(psum, pcnt, fcw, fcb, out);
}

// Round 9
// 490.494 us; speedup vs baseline: 1.1403x; 1.0512x over previous
//
#include <hip/hip_runtime.h>
#include <math.h>

#define N_NODES 50000
#define N_EDGES 800000
#define N_GRAPHS 64
#define F_INN 128
#define F_HID 192
#define F_OUTT 128
#define N_CLS 10
#define POOL_CHUNK 128

typedef short short8 __attribute__((ext_vector_type(8)));
typedef float f32x4 __attribute__((ext_vector_type(4)));

static __device__ inline unsigned short f2bf(float f) {
    unsigned int u = __float_as_uint(f);
    unsigned int r = (u + 0x7FFFu + ((u >> 16) & 1u)) >> 16;  // RNE
    return (unsigned short)r;
}
static __device__ inline float bf2f(unsigned short h) {
    return __uint_as_float(((unsigned int)h) << 16);
}

// ---------------- CSR build ----------------
// k_deg records each edge's rank (atomic return is free); scatter is then
// atomic-free. 1 edge/thread (TLP > ILP for random atomics — round-6 lesson).
__global__ void k_deg(const int* __restrict__ row, int* __restrict__ cnt,
                      int* __restrict__ rank) {
    int e = blockIdx.x * 256 + threadIdx.x;
    if (e < N_EDGES) rank[e] = atomicAdd(&cnt[row[e]], 1);
}

__global__ void k_scan1(const int* __restrict__ cnt, int* __restrict__ rp,
                        int* __restrict__ part, float* __restrict__ dis) {
    __shared__ int s[256];
    int base = blockIdx.x * 512;
    int i0 = base + 2 * threadIdx.x;
    int v0 = (i0 < N_NODES) ? cnt[i0] : 0;
    int v1 = (i0 + 1 < N_NODES) ? cnt[i0 + 1] : 0;
    if (i0 < N_NODES) dis[i0] = v0 > 0 ? rsqrtf((float)v0) : 0.f;
    if (i0 + 1 < N_NODES) dis[i0 + 1] = v1 > 0 ? rsqrtf((float)v1) : 0.f;
    int tsum = v0 + v1;
    s[threadIdx.x] = tsum;
    __syncthreads();
    for (int off = 1; off < 256; off <<= 1) {
        int val = (threadIdx.x >= off) ? s[threadIdx.x - off] : 0;
        __syncthreads();
        s[threadIdx.x] += val;
        __syncthreads();
    }
    int excl = s[threadIdx.x] - tsum;
    if (i0 < N_NODES) rp[i0] = excl;
    if (i0 + 1 < N_NODES) rp[i0 + 1] = excl + v0;
    if (threadIdx.x == 255) part[blockIdx.x] = s[255];
}

__global__ void k_scan2(int* __restrict__ part, int nb) {
    __shared__ int s[128];
    int t = threadIdx.x;
    int v = (t < nb) ? part[t] : 0;
    s[t] = v;
    __syncthreads();
    for (int off = 1; off < 128; off <<= 1) {
        int val = (t >= off) ? s[t - off] : 0;
        __syncthreads();
        s[t] += val;
        __syncthreads();
    }
    if (t < nb) part[t] = s[t] - v;  // exclusive
}

__global__ void k_scan3(int* __restrict__ rp, const int* __restrict__ part) {
    int add = part[blockIdx.x];
    int i0 = blockIdx.x * 512 + 2 * threadIdx.x;
    if (i0 < N_NODES) rp[i0] += add;
    if (i0 + 1 < N_NODES) rp[i0 + 1] += add;
    if (blockIdx.x == 0 && threadIdx.x == 0) rp[N_NODES] = N_EDGES;
}

// packed CSR payload: (col, weight-bits). Atomic-free: pos = rp[r] + rank[e].
__global__ void k_scatter(const int* __restrict__ row, const int* __restrict__ col,
                          const float* __restrict__ dis, const int* __restrict__ rp,
                          const int* __restrict__ rank, int2* __restrict__ cw) {
    int e = blockIdx.x * 256 + threadIdx.x;
    if (e < N_EDGES) {
        int r = row[e], c = col[e];
        int pos = rp[r] + rank[e];
        int2 v;
        v.x = c;
        v.y = __float_as_int(-dis[r] * dis[c]);
        cw[pos] = v;
    }
}

// ---------------- fused fp32->bf16 conversions (x + 3 transposed W) --------
// Chebyshev weight folding: out = Tx0(W0-W2) + G1*W1 + G2*(2*W2), where
// G1 = L*Tx0, G2 = L*G1 — so the SpMV never needs alpha/beta epilogues.
#define NX (N_NODES * F_INN)
#define NW1 (3 * 128 * 192)
#define NW2 (3 * 192 * 192)
#define NW3 (3 * 192 * 128)
__global__ void k_convAll(const float* __restrict__ x, const float* __restrict__ W1,
                          const float* __restrict__ W2, const float* __restrict__ W3,
                          unsigned short* __restrict__ xb,
                          unsigned short* __restrict__ Wt1,
                          unsigned short* __restrict__ Wt2,
                          unsigned short* __restrict__ Wt3) {
    int idx = blockIdx.x * 256 + threadIdx.x;
    if (idx < NX) {
        xb[idx] = f2bf(x[idx]);
        return;
    }
    idx -= NX;
    if (idx < NW1) {  // W[j][k][n] -> Wt[j][n][k], Fin=128, Fout=192
        int per = 128 * 192;
        int j = idx / per, r = idx - j * per;
        int k = r / 192, n = r - k * 192;
        float v = (j == 0) ? (W1[idx] - W1[idx + 2 * per])
                           : (j == 2 ? 2.f * W1[idx] : W1[idx]);
        Wt1[j * per + n * 128 + k] = f2bf(v);
        return;
    }
    idx -= NW1;
    if (idx < NW2) {  // Fin=192, Fout=192
        int per = 192 * 192;
        int j = idx / per, r = idx - j * per;
        int k = r / 192, n = r - k * 192;
        float v = (j == 0) ? (W2[idx] - W2[idx + 2 * per])
                           : (j == 2 ? 2.f * W2[idx] : W2[idx]);
        Wt2[j * per + n * 192 + k] = f2bf(v);
        return;
    }
    idx -= NW2;
    if (idx < NW3) {  // Fin=192, Fout=128
        int per = 192 * 128;
        int j = idx / per, r = idx - j * per;
        int k = r / 128, n = r - k * 128;
        float v = (j == 0) ? (W3[idx] - W3[idx + 2 * per])
                           : (j == 2 ? 2.f * W3[idx] : W3[idx]);
        Wt3[j * per + n * 192 + k] = f2bf(v);
    }
}

// ---------------- SpMV (bf16 in/out, fp32 accum): y = L_hat @ h -----------
// One wave per row; lane l owns feats {2l,2l+1} (uint gather) + 128+l for
// F=192. Wave-uniform edge metadata via readfirstlane; unroll x8.
// NOTE (round 8): this kernel sits at its structural floor — FETCH ==
// h-size x 8 XCDs (compulsory replication) at the ~3.7 TB/s fabric ceiling.
template <int F>
__global__ void k_spmv(const int* __restrict__ rp, const int2* __restrict__ cw,
                       const unsigned short* __restrict__ h,
                       unsigned short* __restrict__ y) {
    constexpr bool EX = (F > 128);
    constexpr int FU = F / 2;  // uints per row
    int wave = threadIdx.x >> 6;
    int lane = threadIdx.x & 63;
    int r = blockIdx.x * 4 + wave;
    if (r >= N_NODES) return;
    int e0 = __builtin_amdgcn_readfirstlane(rp[r]);
    int e1 = __builtin_amdgcn_readfirstlane(rp[r + 1]);
    const unsigned int* hu = (const unsigned int*)h;
    float a0 = 0.f, a1 = 0.f, a2 = 0.f;
    int e = e0;
    for (; e + 8 <= e1; e += 8) {
        int colv[8];
        float wv[8];
#pragma unroll
        for (int u = 0; u < 8; u++) {
            int2 p = cw[e + u];
            colv[u] = __builtin_amdgcn_readfirstlane(p.x);
            wv[u] = __uint_as_float(__builtin_amdgcn_readfirstlane(p.y));
        }
        unsigned int g[8];
        unsigned short s[8];
#pragma unroll
        for (int u = 0; u < 8; u++) {
            g[u] = hu[colv[u] * FU + lane];
            if constexpr (EX) s[u] = h[colv[u] * F + 128 + lane];
        }
#pragma unroll
        for (int u = 0; u < 8; u++) {
            a0 += wv[u] * bf2f((unsigned short)g[u]);
            a1 += wv[u] * bf2f((unsigned short)(g[u] >> 16));
            if constexpr (EX) a2 += wv[u] * bf2f(s[u]);
        }
    }
    for (; e + 4 <= e1; e += 4) {
        int colv[4];
        float wv[4];
#pragma unroll
        for (int u = 0; u < 4; u++) {
            int2 p = cw[e + u];
            colv[u] = __builtin_amdgcn_readfirstlane(p.x);
            wv[u] = __uint_as_float(__builtin_amdgcn_readfirstlane(p.y));
        }
        unsigned int g[4];
        unsigned short s[4];
#pragma unroll
        for (int u = 0; u < 4; u++) {
            g[u] = hu[colv[u] * FU + lane];
            if constexpr (EX) s[u] = h[colv[u] * F + 128 + lane];
        }
#pragma unroll
        for (int u = 0; u < 4; u++) {
            a0 += wv[u] * bf2f((unsigned short)g[u]);
            a1 += wv[u] * bf2f((unsigned short)(g[u] >> 16));
            if constexpr (EX) a2 += wv[u] * bf2f(s[u]);
        }
    }
    for (; e < e1; e++) {
        int2 p = cw[e];
        int c = __builtin_amdgcn_readfirstlane(p.x);
        float w = __uint_as_float(__builtin_amdgcn_readfirstlane(p.y));
        unsigned int g = hu[c * FU + lane];
        a0 += w * bf2f((unsigned short)g);
        a1 += w * bf2f((unsigned short)(g >> 16));
        if constexpr (EX) a2 += w * bf2f(h[c * F + 128 + lane]);
    }
    ((unsigned int*)y)[r * FU + lane] =
        (unsigned int)f2bf(a0) | ((unsigned int)f2bf(a1) << 16);
    if constexpr (EX) y[r * F + 128 + lane] = f2bf(a2);
}

// ---------------- fused 3-matrix bf16 MFMA GEMM ----------------
// C = A0@W'[0]+A1@W'[1]+A2@W'[2]+bias. One block owns the FULL Fout width
// (round-9: N-tiled grid re-read A across XCDs — blocks sharing an M-tile
// land on different XCDs, so A re-reads were compulsory fabric fills).
// Block: 256 thr = 4 waves; tile M=128 x N=Fout; wave = 32 rows.
// LDS stride 40 shorts breaks pow-2 conflicts.
template <int Fin, int Fout>
__global__ __launch_bounds__(256) void k_gemm3(
    const unsigned short* __restrict__ A0, const unsigned short* __restrict__ A1,
    const unsigned short* __restrict__ A2, const unsigned short* __restrict__ Wt,
    const float* __restrict__ bias, unsigned short* __restrict__ C) {
    constexpr int NF = Fout / 16;   // N-fragments per wave row
    constexpr int BP = Fout / 64;   // B staging passes
    __shared__ unsigned short As[128 * 40];
    __shared__ unsigned short Bs[Fout * 40];
    int t = threadIdx.x;
    int w = t >> 6;
    int lane = t & 63;
    int ml = lane & 15;
    int quad = lane >> 4;
    int mBase = blockIdx.x * 128;
    constexpr int per = Fin * Fout;

    f32x4 acc[2][NF];
#pragma unroll
    for (int i = 0; i < 2; i++)
#pragma unroll
        for (int jn = 0; jn < NF; jn++) acc[i][jn] = (f32x4){0.f, 0.f, 0.f, 0.f};

    int srow = t >> 2;   // 0..63
    int schunk = t & 3;  // 16B chunk within 32-k slab
    constexpr int nChunks = (3 * Fin) >> 5;

    for (int ch = 0; ch < nChunks; ch++) {
        int kg = ch << 5;
        int j = kg / Fin;
        int kk = kg - j * Fin;
        const unsigned short* Aj = (j == 0) ? A0 : (j == 1) ? A1 : A2;
        if (ch > 0) __syncthreads();
#pragma unroll
        for (int pass = 0; pass < 2; pass++) {
            int row = srow + pass * 64;
            int gm = mBase + row;
            uint4 v = {0u, 0u, 0u, 0u};
            if (gm < N_NODES)
                v = *(const uint4*)(Aj + (size_t)gm * Fin + kk + schunk * 8);
            *(uint4*)&As[row * 40 + schunk * 8] = v;
        }
#pragma unroll
        for (int pass = 0; pass < BP; pass++) {
            int row = srow + pass * 64;  // n index 0..Fout-1
            const unsigned short* src =
                Wt + (size_t)j * per + (size_t)row * Fin + kk + schunk * 8;
            *(uint4*)&Bs[row * 40 + schunk * 8] = *(const uint4*)src;
        }
        __syncthreads();

        short8 afr[2];
#pragma unroll
        for (int i = 0; i < 2; i++)
            afr[i] = *(const short8*)&As[(w * 32 + i * 16 + ml) * 40 + quad * 8];
#pragma unroll
        for (int jn = 0; jn < NF; jn++) {
            short8 bfr = *(const short8*)&Bs[(jn * 16 + ml) * 40 + quad * 8];
#pragma unroll
            for (int i = 0; i < 2; i++)
                acc[i][jn] = __builtin_amdgcn_mfma_f32_16x16x32_bf16(
                    afr[i], bfr, acc[i][jn], 0, 0, 0);
        }
    }

    float biasv[NF];
#pragma unroll
    for (int jn = 0; jn < NF; jn++) biasv[jn] = bias[jn * 16 + ml];

#pragma unroll
    for (int i = 0; i < 2; i++) {
#pragma unroll
        for (int r = 0; r < 4; r++) {
            int m = mBase + w * 32 + i * 16 + quad * 4 + r;
            if (m < N_NODES) {
                unsigned short* cp = C + (size_t)m * Fout + ml;
#pragma unroll
                for (int jn = 0; jn < NF; jn++)
                    cp[jn * 16] = f2bf(acc[i][jn][r] + biasv[jn]);
            }
        }
    }
}

// ---------------- pooling: chunked partial sums + atomics ----------------
__global__ void k_pool_partial(const unsigned short* __restrict__ h,
                               const int* __restrict__ batch,
                               float* __restrict__ psum, int* __restrict__ pcnt) {
    int f = threadIdx.x;  // 128
    int n0 = blockIdx.x * POOL_CHUNK;
    int n1 = n0 + POOL_CHUNK;
    if (n1 > N_NODES) n1 = N_NODES;
    if (n0 >= N_NODES) return;
    int curg = batch[n0];
    float acc = 0.f;
    int run = 0;
    for (int n = n0; n < n1; n++) {
        int g = batch[n];
        if (g != curg) {
            atomicAdd(&psum[curg * F_OUTT + f], acc);
            if (f == 0) atomicAdd(&pcnt[curg], run);
            acc = 0.f;
            run = 0;
            curg = g;
        }
        acc += bf2f(h[(size_t)n * F_OUTT + f]);
        run++;
    }
    atomicAdd(&psum[curg * F_OUTT + f], acc);
    if (f == 0) atomicAdd(&pcnt[curg], run);
}

__global__ void k_head(const float* __restrict__ psum, const int* __restrict__ pcnt,
                       const float* __restrict__ fcw, const float* __restrict__ fcb,
                       float* __restrict__ out) {
    int g = blockIdx.x;
    int c = threadIdx.x;  // 64 threads, lanes >= N_CLS idle
    __shared__ float sl[N_CLS];
    float inv = 1.f / fmaxf((float)pcnt[g], 1.f);
    float l = 0.f;
    if (c < N_CLS) {
        l = fcb[c];
        for (int k = 0; k < F_OUTT; k++)
            l += psum[g * F_OUTT + k] * inv * fcw[k * N_CLS + c];
        sl[c] = l;
    }
    __syncthreads();
    if (c < N_CLS) {
        float m = -1e30f;
        for (int i = 0; i < N_CLS; i++) m = fmaxf(m, sl[i]);
        float s = 0.f;
        for (int i = 0; i < N_CLS; i++) s += expf(sl[i] - m);
        out[g * N_CLS + c] = l - m - logf(s);
    }
}

extern "C" void kernel_launch(void* const* d_in, const int* in_sizes, int n_in,
                              void* d_out, int out_size, void* d_ws, size_t ws_size,
                              hipStream_t stream) {
    const float* x = (const float*)d_in[0];
    const int* ei = (const int*)d_in[1];
    const int* batch = (const int*)d_in[2];
    const float* W1 = (const float*)d_in[3];
    const float* b1 = (const float*)d_in[4];
    const float* W2 = (const float*)d_in[5];
    const float* b2 = (const float*)d_in[6];
    const float* W3 = (const float*)d_in[7];
    const float* b3 = (const float*)d_in[8];
    const float* fcw = (const float*)d_in[9];
    const float* fcb = (const float*)d_in[10];
    float* out = (float*)d_out;
    const int* row = ei;
    const int* col = ei + N_EDGES;

    char* p = (char*)d_ws;
    auto carve = [&](size_t bytes) {
        char* q = p;
        p += (bytes + 255) & ~(size_t)255;
        return q;
    };
    int* cnt = (int*)carve(N_NODES * 4);
    int* rank = (int*)carve((size_t)N_EDGES * 4);
    float* dis = (float*)carve(N_NODES * 4);
    int* rp = (int*)carve((N_NODES + 1) * 4);
    int* part = (int*)carve(128 * 4);
    int2* cw = (int2*)carve((size_t)N_EDGES * 8);
    unsigned short* xb = (unsigned short*)carve((size_t)N_NODES * F_INN * 2);
    size_t hbytes = (size_t)N_NODES * 192 * 2;
    unsigned short* bufA = (unsigned short*)carve(hbytes);
    unsigned short* bufB = (unsigned short*)carve(hbytes);
    unsigned short* bufC = (unsigned short*)carve(hbytes);
    unsigned short* bufD = (unsigned short*)carve(hbytes);
    unsigned short* Wt1 = (unsigned short*)carve(NW1 * 2);
    unsigned short* Wt2 = (unsigned short*)carve(NW2 * 2);
    unsigned short* Wt3 = (unsigned short*)carve(NW3 * 2);
    float* psum = (float*)carve(N_GRAPHS * F_OUTT * 4);
    int* pcnt = (int*)carve(N_GRAPHS * 4);

    hipMemsetAsync(cnt, 0, N_NODES * 4, stream);
    hipMemsetAsync(psum, 0, N_GRAPHS * F_OUTT * 4, stream);
    hipMemsetAsync(pcnt, 0, N_GRAPHS * 4, stream);

    k_deg<<<(N_EDGES + 255) / 256, 256, 0, stream>>>(row, cnt, rank);
    int nb = (N_NODES + 511) / 512;  // 98
    k_scan1<<<nb, 256, 0, stream>>>(cnt, rp, part, dis);
    k_scan2<<<1, 128, 0, stream>>>(part, nb);
    k_scan3<<<nb, 256, 0, stream>>>(rp, part);
    k_scatter<<<(N_EDGES + 255) / 256, 256, 0, stream>>>(row, col, dis, rp, rank, cw);

    {
        int tot = NX + NW1 + NW2 + NW3;
        k_convAll<<<(tot + 255) / 256, 256, 0, stream>>>(x, W1, W2, W3, xb, Wt1, Wt2,
                                                         Wt3);
    }

    const int spmvGrid = (N_NODES + 3) / 4;
    const int gemmGrid = (N_NODES + 127) / 128;

    // Layer 1: G1 = L x, G2 = L G1; out = x(W0-W2) + G1 W1 + G2 (2W2) + b
    k_spmv<128><<<spmvGrid, 256, 0, stream>>>(rp, cw, xb, bufB);
    k_spmv<128><<<spmvGrid, 256, 0, stream>>>(rp, cw, bufB, bufC);
    k_gemm3<128, 192><<<gemmGrid, 256, 0, stream>>>(xb, bufB, bufC, Wt1, b1, bufA);
    // Layer 2
    k_spmv<192><<<spmvGrid, 256, 0, stream>>>(rp, cw, bufA, bufB);
    k_spmv<192><<<spmvGrid, 256, 0, stream>>>(rp, cw, bufB, bufC);
    k_gemm3<192, 192><<<gemmGrid, 256, 0, stream>>>(bufA, bufB, bufC, Wt2, b2, bufD);
    // Layer 3
    k_spmv<192><<<spmvGrid, 256, 0, stream>>>(rp, cw, bufD, bufB);
    k_spmv<192><<<spmvGrid, 256, 0, stream>>>(rp, cw, bufB, bufC);
    k_gemm3<192, 128><<<gemmGrid, 256, 0, stream>>>(bufD, bufB, bufC, Wt3, b3, bufA);

    k_pool_partial<<<(N_NODES + POOL_CHUNK - 1) / POOL_CHUNK, F_OUTT, 0, stream>>>(
        bufA, batch, psum, pcnt);
    k_head<<<N_GRAPHS, 64, 0, stream>>>(psum, pcnt, fcw, fcb, out);
}

// Round 10
// 457.590 us; speedup vs baseline: 1.2223x; 1.0719x over previous
//
#include <hip/hip_runtime.h>
#include <math.h>

#define N_NODES 50000
#define N_EDGES 800000
#define N_GRAPHS 64
#define F_INN 128
#define F_HID 192
#define F_OUTT 128
#define N_CLS 10

typedef short short8 __attribute__((ext_vector_type(8)));
typedef float f32x4 __attribute__((ext_vector_type(4)));

static __device__ inline unsigned short f2bf(float f) {
    unsigned int u = __float_as_uint(f);
    unsigned int r = (u + 0x7FFFu + ((u >> 16) & 1u)) >> 16;  // RNE
    return (unsigned short)r;
}
static __device__ inline float bf2f(unsigned short h) {
    return __uint_as_float(((unsigned int)h) << 16);
}

// ---------------- CSR build ----------------
// k_deg records each edge's rank (atomic return is free); scatter is then
// atomic-free. 1 edge/thread (TLP > ILP for random atomics — round-6 lesson).
__global__ void k_deg(const int* __restrict__ row, int* __restrict__ cnt,
                      int* __restrict__ rank) {
    int e = blockIdx.x * 256 + threadIdx.x;
    if (e < N_EDGES) rank[e] = atomicAdd(&cnt[row[e]], 1);
}

__global__ void k_scan1(const int* __restrict__ cnt, int* __restrict__ rp,
                        int* __restrict__ part, float* __restrict__ dis) {
    __shared__ int s[256];
    int base = blockIdx.x * 512;
    int i0 = base + 2 * threadIdx.x;
    int v0 = (i0 < N_NODES) ? cnt[i0] : 0;
    int v1 = (i0 + 1 < N_NODES) ? cnt[i0 + 1] : 0;
    if (i0 < N_NODES) dis[i0] = v0 > 0 ? rsqrtf((float)v0) : 0.f;
    if (i0 + 1 < N_NODES) dis[i0 + 1] = v1 > 0 ? rsqrtf((float)v1) : 0.f;
    int tsum = v0 + v1;
    s[threadIdx.x] = tsum;
    __syncthreads();
    for (int off = 1; off < 256; off <<= 1) {
        int val = (threadIdx.x >= off) ? s[threadIdx.x - off] : 0;
        __syncthreads();
        s[threadIdx.x] += val;
        __syncthreads();
    }
    int excl = s[threadIdx.x] - tsum;
    if (i0 < N_NODES) rp[i0] = excl;
    if (i0 + 1 < N_NODES) rp[i0 + 1] = excl + v0;
    if (threadIdx.x == 255) part[blockIdx.x] = s[255];
}

// scan phases 2+3 fused: each block reduces part[0..b-1] itself (nb<=128).
__global__ void k_scan3(int* __restrict__ rp, const int* __restrict__ part,
                        int nb) {
    __shared__ int s[128];
    int t = threadIdx.x;
    int b = blockIdx.x;
    if (t < 128) s[t] = (t < b && t < nb) ? part[t] : 0;
    __syncthreads();
    for (int off = 64; off > 0; off >>= 1) {
        if (t < off) s[t] += s[t + off];
        __syncthreads();
    }
    int add = s[0];
    int i0 = b * 512 + 2 * t;
    if (i0 < N_NODES) rp[i0] += add;
    if (i0 + 1 < N_NODES) rp[i0 + 1] += add;
    if (b == 0 && t == 0) rp[N_NODES] = N_EDGES;
}

// packed CSR payload: (col, weight-bits). Atomic-free: pos = rp[r] + rank[e].
__global__ void k_scatter(const int* __restrict__ row, const int* __restrict__ col,
                          const float* __restrict__ dis, const int* __restrict__ rp,
                          const int* __restrict__ rank, int2* __restrict__ cw) {
    int e = blockIdx.x * 256 + threadIdx.x;
    if (e < N_EDGES) {
        int r = row[e], c = col[e];
        int pos = rp[r] + rank[e];
        int2 v;
        v.x = c;
        v.y = __float_as_int(-dis[r] * dis[c]);
        cw[pos] = v;
    }
}

// ---------------- fused fp32->bf16 conversions + workspace zeroing ---------
// Chebyshev weight folding: out = Tx0(W0-W2) + G1*W1 + G2*(2*W2), where
// G1 = L*Tx0, G2 = L*G1 — SpMV needs no alpha/beta epilogues.
// Tail of the index space zeroes cnt and psum (replaces hipMemsetAsync).
#define NX (N_NODES * F_INN)
#define NW1 (3 * 128 * 192)
#define NW2 (3 * 192 * 192)
#define NW3 (3 * 192 * 128)
#define NPS (N_GRAPHS * F_OUTT)
__global__ void k_convAll(const float* __restrict__ x, const float* __restrict__ W1,
                          const float* __restrict__ W2, const float* __restrict__ W3,
                          unsigned short* __restrict__ xb,
                          unsigned short* __restrict__ Wt1,
                          unsigned short* __restrict__ Wt2,
                          unsigned short* __restrict__ Wt3,
                          int* __restrict__ cnt, float* __restrict__ psum) {
    int idx = blockIdx.x * 256 + threadIdx.x;
    if (idx < NX) {
        xb[idx] = f2bf(x[idx]);
        return;
    }
    idx -= NX;
    if (idx < NW1) {  // W[j][k][n] -> Wt[j][n][k], Fin=128, Fout=192
        int per = 128 * 192;
        int j = idx / per, r = idx - j * per;
        int k = r / 192, n = r - k * 192;
        float v = (j == 0) ? (W1[idx] - W1[idx + 2 * per])
                           : (j == 2 ? 2.f * W1[idx] : W1[idx]);
        Wt1[j * per + n * 128 + k] = f2bf(v);
        return;
    }
    idx -= NW1;
    if (idx < NW2) {  // Fin=192, Fout=192
        int per = 192 * 192;
        int j = idx / per, r = idx - j * per;
        int k = r / 192, n = r - k * 192;
        float v = (j == 0) ? (W2[idx] - W2[idx + 2 * per])
                           : (j == 2 ? 2.f * W2[idx] : W2[idx]);
        Wt2[j * per + n * 192 + k] = f2bf(v);
        return;
    }
    idx -= NW2;
    if (idx < NW3) {  // Fin=192, Fout=128
        int per = 192 * 128;
        int j = idx / per, r = idx - j * per;
        int k = r / 128, n = r - k * 128;
        float v = (j == 0) ? (W3[idx] - W3[idx + 2 * per])
                           : (j == 2 ? 2.f * W3[idx] : W3[idx]);
        Wt3[j * per + n * 192 + k] = f2bf(v);
        return;
    }
    idx -= NW3;
    if (idx < N_NODES) {
        cnt[idx] = 0;
        return;
    }
    idx -= N_NODES;
    if (idx < NPS) psum[idx] = 0.f;
}

// ---------------- SpMV (bf16 in/out, fp32 accum): y = L_hat @ h -----------
// One wave per row; lane l owns feats {2l,2l+1} (uint gather) + 128+l for
// F=192. Wave-uniform edge metadata via readfirstlane; unroll x8.
// NOTE (round 8): structural floor — FETCH == h-size x 8 XCDs (compulsory
// replication) at the ~3.7 TB/s fabric ceiling.
template <int F>
__global__ void k_spmv(const int* __restrict__ rp, const int2* __restrict__ cw,
                       const unsigned short* __restrict__ h,
                       unsigned short* __restrict__ y) {
    constexpr bool EX = (F > 128);
    constexpr int FU = F / 2;  // uints per row
    int wave = threadIdx.x >> 6;
    int lane = threadIdx.x & 63;
    int r = blockIdx.x * 4 + wave;
    if (r >= N_NODES) return;
    int e0 = __builtin_amdgcn_readfirstlane(rp[r]);
    int e1 = __builtin_amdgcn_readfirstlane(rp[r + 1]);
    const unsigned int* hu = (const unsigned int*)h;
    float a0 = 0.f, a1 = 0.f, a2 = 0.f;
    int e = e0;
    for (; e + 8 <= e1; e += 8) {
        int colv[8];
        float wv[8];
#pragma unroll
        for (int u = 0; u < 8; u++) {
            int2 p = cw[e + u];
            colv[u] = __builtin_amdgcn_readfirstlane(p.x);
            wv[u] = __uint_as_float(__builtin_amdgcn_readfirstlane(p.y));
        }
        unsigned int g[8];
        unsigned short s[8];
#pragma unroll
        for (int u = 0; u < 8; u++) {
            g[u] = hu[colv[u] * FU + lane];
            if constexpr (EX) s[u] = h[colv[u] * F + 128 + lane];
        }
#pragma unroll
        for (int u = 0; u < 8; u++) {
            a0 += wv[u] * bf2f((unsigned short)g[u]);
            a1 += wv[u] * bf2f((unsigned short)(g[u] >> 16));
            if constexpr (EX) a2 += wv[u] * bf2f(s[u]);
        }
    }
    for (; e + 4 <= e1; e += 4) {
        int colv[4];
        float wv[4];
#pragma unroll
        for (int u = 0; u < 4; u++) {
            int2 p = cw[e + u];
            colv[u] = __builtin_amdgcn_readfirstlane(p.x);
            wv[u] = __uint_as_float(__builtin_amdgcn_readfirstlane(p.y));
        }
        unsigned int g[4];
        unsigned short s[4];
#pragma unroll
        for (int u = 0; u < 4; u++) {
            g[u] = hu[colv[u] * FU + lane];
            if constexpr (EX) s[u] = h[colv[u] * F + 128 + lane];
        }
#pragma unroll
        for (int u = 0; u < 4; u++) {
            a0 += wv[u] * bf2f((unsigned short)g[u]);
            a1 += wv[u] * bf2f((unsigned short)(g[u] >> 16));
            if constexpr (EX) a2 += wv[u] * bf2f(s[u]);
        }
    }
    for (; e < e1; e++) {
        int2 p = cw[e];
        int c = __builtin_amdgcn_readfirstlane(p.x);
        float w = __uint_as_float(__builtin_amdgcn_readfirstlane(p.y));
        unsigned int g = hu[c * FU + lane];
        a0 += w * bf2f((unsigned short)g);
        a1 += w * bf2f((unsigned short)(g >> 16));
        if constexpr (EX) a2 += w * bf2f(h[c * F + 128 + lane]);
    }
    ((unsigned int*)y)[r * FU + lane] =
        (unsigned int)f2bf(a0) | ((unsigned int)f2bf(a1) << 16);
    if constexpr (EX) y[r * F + 128 + lane] = f2bf(a2);
}

// ---------------- fused 3-matrix bf16 MFMA GEMM ----------------
// C = A0@W'[0]+A1@W'[1]+A2@W'[2]+bias. One block owns the FULL Fout width
// (N-tiled grids re-read A across XCDs — compulsory fabric fills).
// Block: 256 thr = 4 waves; tile M=128 x N=Fout; wave = 32 rows.
// FUSE_POOL: skip the C write; pool the fp32 tile into psum instead
// (layer-3 output is consumed only by global mean pool). Fast path when a
// wave's 32 rows share one graph: in-lane row-sum + shfl_xor quad-reduce
// -> 8 atomics per wave; boundary waves take per-row atomics.
template <int Fin, int Fout, bool FUSE_POOL>
__global__ __launch_bounds__(256) void k_gemm3(
    const unsigned short* __restrict__ A0, const unsigned short* __restrict__ A1,
    const unsigned short* __restrict__ A2, const unsigned short* __restrict__ Wt,
    const float* __restrict__ bias, unsigned short* __restrict__ C,
    const int* __restrict__ batch, float* __restrict__ psum) {
    constexpr int NF = Fout / 16;  // N-fragments per wave row
    constexpr int BP = Fout / 64;  // B staging passes
    __shared__ unsigned short As[128 * 40];
    __shared__ unsigned short Bs[Fout * 40];
    int t = threadIdx.x;
    int w = t >> 6;
    int lane = t & 63;
    int ml = lane & 15;
    int quad = lane >> 4;
    int mBase = blockIdx.x * 128;
    constexpr int per = Fin * Fout;

    f32x4 acc[2][NF];
#pragma unroll
    for (int i = 0; i < 2; i++)
#pragma unroll
        for (int jn = 0; jn < NF; jn++) acc[i][jn] = (f32x4){0.f, 0.f, 0.f, 0.f};

    int srow = t >> 2;   // 0..63
    int schunk = t & 3;  // 16B chunk within 32-k slab
    constexpr int nChunks = (3 * Fin) >> 5;

    for (int ch = 0; ch < nChunks; ch++) {
        int kg = ch << 5;
        int j = kg / Fin;
        int kk = kg - j * Fin;
        const unsigned short* Aj = (j == 0) ? A0 : (j == 1) ? A1 : A2;
        if (ch > 0) __syncthreads();
#pragma unroll
        for (int pass = 0; pass < 2; pass++) {
            int row = srow + pass * 64;
            int gm = mBase + row;
            uint4 v = {0u, 0u, 0u, 0u};
            if (gm < N_NODES)
                v = *(const uint4*)(Aj + (size_t)gm * Fin + kk + schunk * 8);
            *(uint4*)&As[row * 40 + schunk * 8] = v;
        }
#pragma unroll
        for (int pass = 0; pass < BP; pass++) {
            int row = srow + pass * 64;  // n index 0..Fout-1
            const unsigned short* src =
                Wt + (size_t)j * per + (size_t)row * Fin + kk + schunk * 8;
            *(uint4*)&Bs[row * 40 + schunk * 8] = *(const uint4*)src;
        }
        __syncthreads();

        short8 afr[2];
#pragma unroll
        for (int i = 0; i < 2; i++)
            afr[i] = *(const short8*)&As[(w * 32 + i * 16 + ml) * 40 + quad * 8];
#pragma unroll
        for (int jn = 0; jn < NF; jn++) {
            short8 bfr = *(const short8*)&Bs[(jn * 16 + ml) * 40 + quad * 8];
#pragma unroll
            for (int i = 0; i < 2; i++)
                acc[i][jn] = __builtin_amdgcn_mfma_f32_16x16x32_bf16(
                    afr[i], bfr, acc[i][jn], 0, 0, 0);
        }
    }

    float biasv[NF];
#pragma unroll
    for (int jn = 0; jn < NF; jn++) biasv[jn] = bias[jn * 16 + ml];

    if constexpr (!FUSE_POOL) {
#pragma unroll
        for (int i = 0; i < 2; i++) {
#pragma unroll
            for (int r = 0; r < 4; r++) {
                int m = mBase + w * 32 + i * 16 + quad * 4 + r;
                if (m < N_NODES) {
                    unsigned short* cp = C + (size_t)m * Fout + ml;
#pragma unroll
                    for (int jn = 0; jn < NF; jn++)
                        cp[jn * 16] = f2bf(acc[i][jn][r] + biasv[jn]);
                }
            }
        }
    } else {
        int m0 = mBase + w * 32;
        if (m0 >= N_NODES) return;
        int mlast = m0 + 31;
        if (mlast >= N_NODES) mlast = N_NODES - 1;
        int g0 = batch[m0];
        int g1 = batch[mlast];
        if (g0 == g1) {
            // fast path: whole wave in one graph
#pragma unroll
            for (int jn = 0; jn < NF; jn++) {
                float pv = 0.f;
#pragma unroll
                for (int i = 0; i < 2; i++)
#pragma unroll
                    for (int r = 0; r < 4; r++) {
                        int m = m0 + i * 16 + quad * 4 + r;
                        if (m < N_NODES) pv += acc[i][jn][r] + biasv[jn];
                    }
                pv += __shfl_xor(pv, 16);
                pv += __shfl_xor(pv, 32);
                if (lane < 16) atomicAdd(&psum[g0 * F_OUTT + ml + jn * 16], pv);
            }
        } else {
            // boundary wave: per-row atomics
#pragma unroll
            for (int i = 0; i < 2; i++)
#pragma unroll
                for (int r = 0; r < 4; r++) {
                    int m = m0 + i * 16 + quad * 4 + r;
                    if (m < N_NODES) {
                        int g = batch[m];
#pragma unroll
                        for (int jn = 0; jn < NF; jn++)
                            atomicAdd(&psum[g * F_OUTT + ml + jn * 16],
                                      acc[i][jn][r] + biasv[jn]);
                    }
                }
        }
    }
}

// ---------------- head: mean + fc + log_softmax ----------------
__global__ void k_head(const float* __restrict__ psum, const int* __restrict__ batch,
                       const float* __restrict__ fcw, const float* __restrict__ fcb,
                       float* __restrict__ out) {
    int g = blockIdx.x;
    int c = threadIdx.x;  // 64 threads, lanes >= N_CLS idle
    __shared__ float sl[N_CLS];
    int a = 0, b = N_NODES;
    while (a < b) { int m = (a + b) >> 1; if (batch[m] < g) a = m + 1; else b = m; }
    int lo = a;
    a = lo; b = N_NODES;
    while (a < b) { int m = (a + b) >> 1; if (batch[m] < g + 1) a = m + 1; else b = m; }
    float inv = 1.f / fmaxf((float)(a - lo), 1.f);
    float l = 0.f;
    if (c < N_CLS) {
        l = fcb[c];
        for (int k = 0; k < F_OUTT; k++)
            l += psum[g * F_OUTT + k] * inv * fcw[k * N_CLS + c];
        sl[c] = l;
    }
    __syncthreads();
    if (c < N_CLS) {
        float m = -1e30f;
        for (int i = 0; i < N_CLS; i++) m = fmaxf(m, sl[i]);
        float s = 0.f;
        for (int i = 0; i < N_CLS; i++) s += expf(sl[i] - m);
        out[g * N_CLS + c] = l - m - logf(s);
    }
}

extern "C" void kernel_launch(void* const* d_in, const int* in_sizes, int n_in,
                              void* d_out, int out_size, void* d_ws, size_t ws_size,
                              hipStream_t stream) {
    const float* x = (const float*)d_in[0];
    const int* ei = (const int*)d_in[1];
    const int* batch = (const int*)d_in[2];
    const float* W1 = (const float*)d_in[3];
    const float* b1 = (const float*)d_in[4];
    const float* W2 = (const float*)d_in[5];
    const float* b2 = (const float*)d_in[6];
    const float* W3 = (const float*)d_in[7];
    const float* b3 = (const float*)d_in[8];
    const float* fcw = (const float*)d_in[9];
    const float* fcb = (const float*)d_in[10];
    float* out = (float*)d_out;
    const int* row = ei;
    const int* col = ei + N_EDGES;

    char* p = (char*)d_ws;
    auto carve = [&](size_t bytes) {
        char* q = p;
        p += (bytes + 255) & ~(size_t)255;
        return q;
    };
    int* cnt = (int*)carve(N_NODES * 4);
    int* rank = (int*)carve((size_t)N_EDGES * 4);
    float* dis = (float*)carve(N_NODES * 4);
    int* rp = (int*)carve((N_NODES + 1) * 4);
    int* part = (int*)carve(128 * 4);
    int2* cw = (int2*)carve((size_t)N_EDGES * 8);
    unsigned short* xb = (unsigned short*)carve((size_t)N_NODES * F_INN * 2);
    size_t hbytes = (size_t)N_NODES * 192 * 2;
    unsigned short* bufA = (unsigned short*)carve(hbytes);
    unsigned short* bufB = (unsigned short*)carve(hbytes);
    unsigned short* bufC = (unsigned short*)carve(hbytes);
    unsigned short* bufD = (unsigned short*)carve(hbytes);
    unsigned short* Wt1 = (unsigned short*)carve(NW1 * 2);
    unsigned short* Wt2 = (unsigned short*)carve(NW2 * 2);
    unsigned short* Wt3 = (unsigned short*)carve(NW3 * 2);
    float* psum = (float*)carve(NPS * 4);

    // conv + zeroing first (replaces all memsets; stream order covers deps)
    {
        int tot = NX + NW1 + NW2 + NW3 + N_NODES + NPS;
        k_convAll<<<(tot + 255) / 256, 256, 0, stream>>>(x, W1, W2, W3, xb, Wt1, Wt2,
                                                         Wt3, cnt, psum);
    }

    k_deg<<<(N_EDGES + 255) / 256, 256, 0, stream>>>(row, cnt, rank);
    int nb = (N_NODES + 511) / 512;  // 98
    k_scan1<<<nb, 256, 0, stream>>>(cnt, rp, part, dis);
    k_scan3<<<nb, 256, 0, stream>>>(rp, part, nb);
    k_scatter<<<(N_EDGES + 255) / 256, 256, 0, stream>>>(row, col, dis, rp, rank, cw);

    const int spmvGrid = (N_NODES + 3) / 4;
    const int gemmGrid = (N_NODES + 127) / 128;

    // Layer 1: G1 = L x, G2 = L G1; out = x(W0-W2) + G1 W1 + G2 (2W2) + b
    k_spmv<128><<<spmvGrid, 256, 0, stream>>>(rp, cw, xb, bufB);
    k_spmv<128><<<spmvGrid, 256, 0, stream>>>(rp, cw, bufB, bufC);
    k_gemm3<128, 192, false><<<gemmGrid, 256, 0, stream>>>(xb, bufB, bufC, Wt1, b1,
                                                           bufA, batch, psum);
    // Layer 2
    k_spmv<192><<<spmvGrid, 256, 0, stream>>>(rp, cw, bufA, bufB);
    k_spmv<192><<<spmvGrid, 256, 0, stream>>>(rp, cw, bufB, bufC);
    k_gemm3<192, 192, false><<<gemmGrid, 256, 0, stream>>>(bufA, bufB, bufC, Wt2, b2,
                                                           bufD, batch, psum);
    // Layer 3: pool fused into epilogue; no C write
    k_spmv<192><<<spmvGrid, 256, 0, stream>>>(rp, cw, bufD, bufB);
    k_spmv<192><<<spmvGrid, 256, 0, stream>>>(rp, cw, bufB, bufC);
    k_gemm3<192, 128, true><<<gemmGrid, 256, 0, stream>>>(bufD, bufB, bufC, Wt3, b3,
                                                          nullptr, batch, psum);

    k_head<<<N_GRAPHS, 64, 0, stream>>>(psum, batch, fcw, fcb, out);
}